// Round 12
// baseline (266.404 us; speedup 1.0000x reference)
//
#include <hip/hip_runtime.h>
#include <hip/hip_fp16.h>
#include <math.h>

#define NN 50000
#define NE 800000
#define NG 256
#define NEG_SLOPE 0.2f
#define GEPS 1e-5f
#define NB 196          // coarse buckets of 256 node-ids (dst >> 8)
#define CAP 6144        // per-bucket segment capacity (mean 4081)
#define EPB 3125        // edges per binA block (256 blocks)
#define SPLIT 8         // row-split for stats/pool partials
#define NLINB 782       // (NN+63)/64 lin blocks
#define ABLK 3321       // (NE+NN+255)/256 alpha blocks

typedef _Float16 f16x8 __attribute__((ext_vector_type(8)));
typedef _Float16 f16x4 __attribute__((ext_vector_type(4)));
typedef float f32x4 __attribute__((ext_vector_type(4)));
typedef float f32x2 __attribute__((ext_vector_type(2)));

__device__ __forceinline__ float lrelu(float v){ return v > 0.f ? v : NEG_SLOPE * v; }

// ---------------- K0: fp16 weight converts + goff + bucket_cnt zero ----------
__global__ __launch_bounds__(256) void k_misc(const float* __restrict__ lin_w,
                                              _Float16* __restrict__ wh,
                                              const float* __restrict__ att1_w,
                                              _Float16* __restrict__ a1w,
                                              const int* __restrict__ batch,
                                              int* __restrict__ goff,
                                              int* __restrict__ gcnt,
                                              int* __restrict__ bucket_cnt) {
  int b = blockIdx.x, tid = threadIdx.x;
  if (b == 0) {
    if (tid < NB) bucket_cnt[tid] = 0;
    int g = tid;
    int lo = 0, hi = NN;
    while (lo < hi) { int mid = (lo + hi) >> 1; if (batch[mid] < g) lo = mid + 1; else hi = mid; }
    int start = lo;
    lo = 0; hi = NN;
    while (lo < hi) { int mid = (lo + hi) >> 1; if (batch[mid] < g + 1) lo = mid + 1; else hi = mid; }
    goff[g] = start;
    gcnt[g] = lo - start;
  } else if (b <= 16) {
    int i0 = (b - 1) * 1024 + tid * 4;
    float4 f = *(const float4*)&lin_w[i0];
    f16x4 h4;
    h4[0] = (_Float16)f.x; h4[1] = (_Float16)f.y; h4[2] = (_Float16)f.z; h4[3] = (_Float16)f.w;
    *(f16x4*)&wh[i0] = h4;
  } else {
    int i0 = (b - 17) * 1024 + tid * 4;
    float4 f = *(const float4*)&att1_w[i0];
    f16x4 h4;
    h4[0] = (_Float16)f.x; h4[1] = (_Float16)f.y; h4[2] = (_Float16)f.z; h4[3] = (_Float16)f.w;
    *(f16x4*)&a1w[i0] = h4;
  }
}

// ---------------- K1 fused: MFMA lin (blocks < NLINB) | binA sort (rest) ------
__device__ __forceinline__ void lin_body(char* smem,
                                         const float* __restrict__ x,
                                         const _Float16* __restrict__ wh,
                                         const float* __restrict__ att_src,
                                         const float* __restrict__ att_dst,
                                         unsigned char* __restrict__ xh8,
                                         float* __restrict__ a_src_n,
                                         float* __restrict__ a_dst_n) {
  unsigned char* s_f8 = (unsigned char*)smem;     // 16 KB
  int w = threadIdx.x >> 6, lane = threadIdx.x & 63;
  int nb = blockIdx.x * 64 + w * 16;
  if (nb >= NN) return;                 // per-wave LDS region; no barriers used
  int am = lane & 15, quad = lane >> 4;
  int wb = w * 4096;

  const float* xr = x + (size_t)(nb + am) * 64 + quad * 8;
  float4 f0 = *(const float4*)(xr);
  float4 f1 = *(const float4*)(xr + 4);
  float4 f2 = *(const float4*)(xr + 32);
  float4 f3 = *(const float4*)(xr + 36);
  f16x8 a0, a1;
  a0[0] = (_Float16)f0.x; a0[1] = (_Float16)f0.y; a0[2] = (_Float16)f0.z; a0[3] = (_Float16)f0.w;
  a0[4] = (_Float16)f1.x; a0[5] = (_Float16)f1.y; a0[6] = (_Float16)f1.z; a0[7] = (_Float16)f1.w;
  a1[0] = (_Float16)f2.x; a1[1] = (_Float16)f2.y; a1[2] = (_Float16)f2.z; a1[3] = (_Float16)f2.w;
  a1[4] = (_Float16)f3.x; a1[5] = (_Float16)f3.y; a1[6] = (_Float16)f3.z; a1[7] = (_Float16)f3.w;

  f32x4 acc[16];
#pragma unroll
  for (int ct = 0; ct < 16; ct++) acc[ct] = (f32x4){0.f, 0.f, 0.f, 0.f};

#pragma unroll
  for (int ct = 0; ct < 16; ct++) {
    const _Float16* wbp = wh + (size_t)(ct * 16 + am) * 64 + quad * 8;
    f16x8 b0 = *(const f16x8*)(wbp);
    f16x8 b1 = *(const f16x8*)(wbp + 32);
    acc[ct] = __builtin_amdgcn_mfma_f32_16x16x32_f16(a0, b0, acc[ct], 0, 0, 0);
    acc[ct] = __builtin_amdgcn_mfma_f32_16x16x32_f16(a1, b1, acc[ct], 0, 0, 0);
  }

  float ps[4][4], pd[4][4];
#pragma unroll
  for (int r = 0; r < 4; r++)
#pragma unroll
    for (int h = 0; h < 4; h++) { ps[r][h] = 0.f; pd[r][h] = 0.f; }
#pragma unroll
  for (int ct = 0; ct < 16; ct++) {
    int c = ct * 16 + am;
    float av = att_src[c];
    float dv = att_dst[c];
    int h = ct >> 2;
#pragma unroll
    for (int r = 0; r < 4; r++) {
      float v = acc[ct][r];
      ps[r][h] += v * av;
      pd[r][h] += v * dv;
    }
  }
#pragma unroll
  for (int r = 0; r < 4; r++)
#pragma unroll
    for (int h = 0; h < 4; h++) {
      float s = ps[r][h], d = pd[r][h];
#pragma unroll
      for (int o = 1; o < 16; o <<= 1) {
        s += __shfl_xor(s, o, 64);
        d += __shfl_xor(d, o, 64);
      }
      if (am == 0) {
        int node = nb + quad * 4 + r;
        a_src_n[node * 4 + h] = s;
        a_dst_n[node * 4 + h] = d;
      }
    }

#pragma unroll
  for (int r = 0; r < 4; r++) {
    uint4 u;
    int t;
    t = __builtin_amdgcn_cvt_pk_fp8_f32(acc[0][r],  acc[1][r],  0, 0);
    t = __builtin_amdgcn_cvt_pk_fp8_f32(acc[2][r],  acc[3][r],  t, 1);
    u.x = (unsigned)t;
    t = __builtin_amdgcn_cvt_pk_fp8_f32(acc[4][r],  acc[5][r],  0, 0);
    t = __builtin_amdgcn_cvt_pk_fp8_f32(acc[6][r],  acc[7][r],  t, 1);
    u.y = (unsigned)t;
    t = __builtin_amdgcn_cvt_pk_fp8_f32(acc[8][r],  acc[9][r],  0, 0);
    t = __builtin_amdgcn_cvt_pk_fp8_f32(acc[10][r], acc[11][r], t, 1);
    u.z = (unsigned)t;
    t = __builtin_amdgcn_cvt_pk_fp8_f32(acc[12][r], acc[13][r], 0, 0);
    t = __builtin_amdgcn_cvt_pk_fp8_f32(acc[14][r], acc[15][r], t, 1);
    u.w = (unsigned)t;
    *(uint4*)&s_f8[wb + (quad * 4 + r) * 256 + am * 16] = u;
  }
#pragma unroll
  for (int p = 0; p < 4; p++) {
    uint4 u = *(const uint4*)&s_f8[wb + p * 1024 + lane * 16];
    *(uint4*)&xh8[(size_t)nb * 256 + p * 1024 + lane * 16] = u;
  }
}

__device__ __forceinline__ void binA_body(char* smem, int b,
                                          const int* __restrict__ ei,
                                          int* __restrict__ bucket_cnt,
                                          int2* __restrict__ ebuf) {
  int2* sorted = (int2*)smem;                         // 25000 B
  int*  hist   = (int*)(smem + 25024);
  int*  lbase  = (int*)(smem + 25824);
  int*  cur    = (int*)(smem + 26624);
  int*  runb   = (int*)(smem + 27424);
  int*  wsum   = (int*)(smem + 28224);
  int tid = threadIdx.x, lane = tid & 63, wid = tid >> 6;
  int e0 = b * EPB, e1 = min(e0 + EPB, NE);
  int n = e1 - e0;
  for (int i = tid; i < NB; i += 256) hist[i] = 0;
  __syncthreads();
  for (int e = e0 + tid; e < e1; e += 256) atomicAdd(&hist[ei[NE + e] >> 8], 1);
  __syncthreads();
  {
    int v = (tid < NB) ? hist[tid] : 0;
    int s = v;
#pragma unroll
    for (int o = 1; o < 64; o <<= 1) { int t = __shfl_up(s, o, 64); if (lane >= o) s += t; }
    if (lane == 63) wsum[wid] = s;
    __syncthreads();
    int wbase = 0;
    for (int k = 0; k < wid; k++) wbase += wsum[k];
    if (tid < NB) {
      int ex = wbase + s - v;
      lbase[tid] = ex;
      cur[tid] = ex;
      runb[tid] = atomicAdd(&bucket_cnt[tid], v);
    }
  }
  __syncthreads();
  for (int e = e0 + tid; e < e1; e += 256) {
    int d = ei[NE + e], s = ei[e];
    int lp = atomicAdd(&cur[d >> 8], 1);
    sorted[lp] = make_int2(d, s);
  }
  __syncthreads();
  for (int i = tid; i < n; i += 256) {
    int2 e = sorted[i];
    int bk = e.x >> 8;
    int slot = runb[bk] + (i - lbase[bk]);
    if (slot < CAP) ebuf[(size_t)bk * CAP + slot] = e;
  }
}

__global__ __launch_bounds__(256) void k_linbin(const float* __restrict__ x,
                                                const _Float16* __restrict__ wh,
                                                const float* __restrict__ att_src,
                                                const float* __restrict__ att_dst,
                                                unsigned char* __restrict__ xh8,
                                                float* __restrict__ a_src_n,
                                                float* __restrict__ a_dst_n,
                                                const int* __restrict__ ei,
                                                int* __restrict__ bucket_cnt,
                                                int2* __restrict__ ebuf) {
  __shared__ __align__(16) char smem[28240];
  if (blockIdx.x < NLINB)
    lin_body(smem, x, wh, att_src, att_dst, xh8, a_src_n, a_dst_n);
  else
    binA_body(smem, blockIdx.x - NLINB, ei, bucket_cnt, ebuf);
}

// ---------------- K2: per-bucket local hist+scan+scatter (inline bscan) -------
__global__ __launch_bounds__(256) void k_binB(const int2* __restrict__ ebuf,
                                              const int* __restrict__ bucket_cnt,
                                              int* __restrict__ deg,
                                              int* __restrict__ offs,
                                              int* __restrict__ src_list) {
  __shared__ int hist[256];
  __shared__ int cur[256];
  __shared__ int wsum[4];
  __shared__ int bbase[NB];
  int b = blockIdx.x, tid = threadIdx.x, lane = tid & 63, wid = tid >> 6;
  {
    int v = (tid < NB) ? min(bucket_cnt[tid], CAP) : 0;
    int s = v;
#pragma unroll
    for (int o = 1; o < 64; o <<= 1) { int t = __shfl_up(s, o, 64); if (lane >= o) s += t; }
    if (lane == 63) wsum[wid] = s;
    __syncthreads();
    int wbase = 0;
    for (int k = 0; k < wid; k++) wbase += wsum[k];
    if (tid < NB) bbase[tid] = wbase + s - v;
  }
  __syncthreads();
  int cnt = min(bucket_cnt[b], CAP);
  int base = bbase[b];
  const int2* seg = ebuf + (size_t)b * CAP;
  hist[tid] = 0;
  __syncthreads();
  for (int i = tid; i < cnt; i += 256) atomicAdd(&hist[seg[i].x & 255], 1);
  __syncthreads();
  int v = hist[tid];
  int s = v;
#pragma unroll
  for (int o = 1; o < 64; o <<= 1) { int t = __shfl_up(s, o, 64); if (lane >= o) s += t; }
  if (lane == 63) wsum[wid] = s;
  __syncthreads();
  int wbase = 0;
  for (int k = 0; k < wid; k++) wbase += wsum[k];
  int excl = wbase + s - v;
  int node = b * 256 + tid;
  if (node < NN) {
    deg[node] = v;
    offs[node] = base + excl;
  }
  cur[tid] = excl;
  __syncthreads();
  for (int i = tid; i < cnt; i += 256) {
    int2 e = seg[i];
    int pos = base + atomicAdd(&cur[e.x & 255], 1);
    src_list[pos] = e.y;
  }
}

// ---------------- K3: GAT, 16B/lane gathers (4 edges/instruction) -------------
// Permuted fp8 layout: row byte (c&15)*16 + (c>>4); lane's 16 bytes at offset
// (lane&15)*16 cover ct=0..15, dword w of them is entirely head w.
// Softmax normalization deferred to epilogue (sum(e*v) * (1/sum e)).
__global__ __launch_bounds__(64) void k_gat(const unsigned char* __restrict__ xh8,
                                            const float* __restrict__ a_src_n,
                                            const float* __restrict__ a_dst_n,
                                            const int* __restrict__ offs,
                                            const int* __restrict__ deg_arr,
                                            const int* __restrict__ src_list,
                                            const float* __restrict__ gat_bias,
                                            __half* __restrict__ x2h,
                                            float* __restrict__ den_inv) {
  __shared__ __align__(16) float s_al[64 * 4];
  __shared__ int s_src[64];
  __shared__ __half s_tr[256];
  int n = blockIdx.x, lane = threadIdx.x;
  int off = offs[n], dg = deg_arr[n], cnt = dg + 1;
  float4 ad = *(const float4*)&a_dst_n[n * 4];
  int am = lane & 15, eg = lane >> 4;
  unsigned loff = (unsigned)am * 16u;

  f32x4 acc[4];
#pragma unroll
  for (int w = 0; w < 4; w++) acc[w] = (f32x4){0.f, 0.f, 0.f, 0.f};
  float s0 = 0.f, s1 = 0.f, s2 = 0.f, s3 = 0.f;

  for (int cb = 0; cb < cnt; cb += 64) {
    int clen = min(64, cnt - cb);
    int pad = (clen + 3) & ~3;
    if (lane < clen) {
      int j = cb + lane;
      int src = (j < dg) ? src_list[off + j] : n;
      float4 as = *(const float4*)&a_src_n[src * 4];
      float e0 = __expf(lrelu(as.x + ad.x));
      float e1 = __expf(lrelu(as.y + ad.y));
      float e2 = __expf(lrelu(as.z + ad.z));
      float e3 = __expf(lrelu(as.w + ad.w));
      s_src[lane] = src;
      *(float4*)&s_al[lane * 4] = make_float4(e0, e1, e2, e3);
      s0 += e0; s1 += e1; s2 += e2; s3 += e3;
    } else if (lane < pad) {
      s_src[lane] = n;
      *(float4*)&s_al[lane * 4] = make_float4(0.f, 0.f, 0.f, 0.f);
    }
    __syncthreads();
    for (int j = 0; j < pad; j += 4) {
      int e = j + eg;
      unsigned oA = ((unsigned)s_src[e] << 8) + loff;
      uint4 r = *(const uint4*)&xh8[oA];
      float4 a4 = *(const float4*)&s_al[e * 4];
      f32x2 l0 = __builtin_amdgcn_cvt_pk_f32_fp8((int)r.x, 0);
      f32x2 h0 = __builtin_amdgcn_cvt_pk_f32_fp8((int)r.x, 1);
      f32x2 l1 = __builtin_amdgcn_cvt_pk_f32_fp8((int)r.y, 0);
      f32x2 h1 = __builtin_amdgcn_cvt_pk_f32_fp8((int)r.y, 1);
      f32x2 l2 = __builtin_amdgcn_cvt_pk_f32_fp8((int)r.z, 0);
      f32x2 h2 = __builtin_amdgcn_cvt_pk_f32_fp8((int)r.z, 1);
      f32x2 l3 = __builtin_amdgcn_cvt_pk_f32_fp8((int)r.w, 0);
      f32x2 h3 = __builtin_amdgcn_cvt_pk_f32_fp8((int)r.w, 1);
      acc[0][0] += a4.x * l0[0]; acc[0][1] += a4.x * l0[1];
      acc[0][2] += a4.x * h0[0]; acc[0][3] += a4.x * h0[1];
      acc[1][0] += a4.y * l1[0]; acc[1][1] += a4.y * l1[1];
      acc[1][2] += a4.y * h1[0]; acc[1][3] += a4.y * h1[1];
      acc[2][0] += a4.z * l2[0]; acc[2][1] += a4.z * l2[1];
      acc[2][2] += a4.z * h2[0]; acc[2][3] += a4.z * h2[1];
      acc[3][0] += a4.w * l3[0]; acc[3][1] += a4.w * l3[1];
      acc[3][2] += a4.w * h3[0]; acc[3][3] += a4.w * h3[1];
    }
    __syncthreads();
  }

  // denominator reduction (lanes beyond edges contributed 0)
#pragma unroll
  for (int o = 32; o >= 1; o >>= 1) {
    s0 += __shfl_xor(s0, o, 64);
    s1 += __shfl_xor(s1, o, 64);
    s2 += __shfl_xor(s2, o, 64);
    s3 += __shfl_xor(s3, o, 64);
  }
  float i0 = 1.f / (s0 + 1e-16f), i1 = 1.f / (s1 + 1e-16f);
  float i2 = 1.f / (s2 + 1e-16f), i3 = 1.f / (s3 + 1e-16f);
  if (lane == 0) *(float4*)&den_inv[n * 4] = make_float4(i0, i1, i2, i3);

  // reduce across the 4 edge subgroups (lane bits 4,5)
#pragma unroll
  for (int w = 0; w < 4; w++)
#pragma unroll
    for (int k = 0; k < 4; k++) {
      float v = acc[w][k];
      v += __shfl_xor(v, 16, 64);
      v += __shfl_xor(v, 32, 64);
      acc[w][k] = v;
    }

  // lane writes head w = eg: channels c = (4*eg+k)*16 + am, scaled by inv-den
  float ivw = (eg == 0) ? i0 : (eg == 1) ? i1 : (eg == 2) ? i2 : i3;
#pragma unroll
  for (int k = 0; k < 4; k++) {
    int c = (4 * eg + k) * 16 + am;
    s_tr[c] = __float2half(acc[eg][k] * ivw + gat_bias[c]);
  }
  __syncthreads();
  uint2 u = *(const uint2*)&s_tr[4 * lane];
  *(uint2*)&x2h[(size_t)n * 256 + 4 * lane] = u;
}

// ---------------- K4 fused: alpha (blocks < ABLK) | stats1 partials (rest) ----
__global__ __launch_bounds__(256) void k_alst(const int* __restrict__ ei,
                                              const float* __restrict__ a_src_n,
                                              const float* __restrict__ a_dst_n,
                                              const float* __restrict__ den_inv,
                                              float* __restrict__ alpha_out,
                                              const __half* __restrict__ x2h,
                                              const int* __restrict__ gcnt,
                                              const int* __restrict__ goff,
                                              float* __restrict__ psumA,
                                              float* __restrict__ psumB) {
  if (blockIdx.x < ABLK) {
    int idx = blockIdx.x * 256 + threadIdx.x;
    if (idx >= NE + NN) return;
    int s, d;
    if (idx < NE) { s = ei[idx]; d = ei[NE + idx]; }
    else          { s = idx - NE; d = s; }
    float4 as = *(const float4*)&a_src_n[s * 4];
    float4 ad = *(const float4*)&a_dst_n[d * 4];
    float4 iv = *(const float4*)&den_inv[d * 4];
    float4 a;
    a.x = __expf(lrelu(as.x + ad.x)) * iv.x;
    a.y = __expf(lrelu(as.y + ad.y)) * iv.y;
    a.z = __expf(lrelu(as.z + ad.z)) * iv.z;
    a.w = __expf(lrelu(as.w + ad.w)) * iv.w;
    *(float4*)&alpha_out[(size_t)idx * 4] = a;
  } else {
    int b = blockIdx.x - ABLK, c = threadIdx.x;
    int g = b >> 3, s = b & 7;
    int cnt = gcnt[g], start = goff[g];
    const __half* p = x2h + (size_t)start * 256 + c;
    float sum = 0.f, sum2 = 0.f;
    int i = s;
    for (; i + 56 < cnt; i += 64) {
      float v0 = __half2float(p[(size_t)(i +  0) * 256]);
      float v1 = __half2float(p[(size_t)(i +  8) * 256]);
      float v2 = __half2float(p[(size_t)(i + 16) * 256]);
      float v3 = __half2float(p[(size_t)(i + 24) * 256]);
      float v4 = __half2float(p[(size_t)(i + 32) * 256]);
      float v5 = __half2float(p[(size_t)(i + 40) * 256]);
      float v6 = __half2float(p[(size_t)(i + 48) * 256]);
      float v7 = __half2float(p[(size_t)(i + 56) * 256]);
      sum += ((v0 + v1) + (v2 + v3)) + ((v4 + v5) + (v6 + v7));
      sum2 += ((v0 * v0 + v1 * v1) + (v2 * v2 + v3 * v3)) +
              ((v4 * v4 + v5 * v5) + (v6 * v6 + v7 * v7));
    }
    for (; i < cnt; i += 8) { float v = __half2float(p[(size_t)i * 256]); sum += v; sum2 += v * v; }
    psumA[b * 256 + c] = sum;
    psumB[b * 256 + c] = sum2;
  }
}

// ---------------- K5: finalize scale/shift -----------------------------------
__global__ __launch_bounds__(256) void k_stats2(const float* __restrict__ psumA,
                                                const float* __restrict__ psumB,
                                                const int* __restrict__ gcnt,
                                                const float* __restrict__ gn_w,
                                                const float* __restrict__ gn_b,
                                                const float* __restrict__ gn_ms,
                                                float* __restrict__ scale_g,
                                                float* __restrict__ shift_g) {
  int g = blockIdx.x, c = threadIdx.x;
  int b0 = g * SPLIT;
  float S = 0.f, S2 = 0.f;
#pragma unroll
  for (int k = 0; k < SPLIT; k++) {
    S  += psumA[(b0 + k) * 256 + c];
    S2 += psumB[(b0 + k) * 256 + c];
  }
  float fc = fmaxf((float)gcnt[g], 1.f);
  float mean = S / fc;
  float mm = mean * gn_ms[c];
  float var = fmaxf(S2 / fc - 2.f * mm * mean + mm * mm, 0.f);
  float sc = gn_w[c] / sqrtf(var + GEPS);
  scale_g[g * 256 + c] = sc;
  shift_g[g * 256 + c] = gn_b[c] - sc * mm;
}

// ---------------- K6: gate MLP via MFMA (16 nodes / wave) --------------------
__global__ __launch_bounds__(256) void k_gate(const __half* __restrict__ x2h,
                                              const int* __restrict__ batch,
                                              const float* __restrict__ scale_g,
                                              const float* __restrict__ shift_g,
                                              const _Float16* __restrict__ a1w,
                                              const float* __restrict__ att1_b,
                                              const float* __restrict__ att2_w,
                                              const float* __restrict__ att2_b,
                                              float* __restrict__ gate_raw) {
  int w = threadIdx.x >> 6, lane = threadIdx.x & 63;
  int nb = blockIdx.x * 64 + w * 16;
  if (nb >= NN) return;                 // no barriers -> safe
  int am = lane & 15, quad = lane >> 4;
  int node = nb + am;
  int g = batch[node];

  const __half*   xp  = x2h + (size_t)node * 256 + quad * 8;
  const float*    scp = scale_g + g * 256 + quad * 8;
  const float*    shp = shift_g + g * 256 + quad * 8;
  const _Float16* bp  = a1w + am * 256 + quad * 8;

  f32x4 acc = (f32x4){0.f, 0.f, 0.f, 0.f};
#pragma unroll
  for (int kb = 0; kb < 8; kb++) {
    f16x8 xv = *(const f16x8*)(xp + kb * 32);
    float4 sc0 = *(const float4*)(scp + kb * 32);
    float4 sc1 = *(const float4*)(scp + kb * 32 + 4);
    float4 sh0 = *(const float4*)(shp + kb * 32);
    float4 sh1 = *(const float4*)(shp + kb * 32 + 4);
    f16x8 a;
    a[0] = (_Float16)fmaxf(sc0.x * (float)xv[0] + sh0.x, 0.f);
    a[1] = (_Float16)fmaxf(sc0.y * (float)xv[1] + sh0.y, 0.f);
    a[2] = (_Float16)fmaxf(sc0.z * (float)xv[2] + sh0.z, 0.f);
    a[3] = (_Float16)fmaxf(sc0.w * (float)xv[3] + sh0.w, 0.f);
    a[4] = (_Float16)fmaxf(sc1.x * (float)xv[4] + sh1.x, 0.f);
    a[5] = (_Float16)fmaxf(sc1.y * (float)xv[5] + sh1.y, 0.f);
    a[6] = (_Float16)fmaxf(sc1.z * (float)xv[6] + sh1.z, 0.f);
    a[7] = (_Float16)fmaxf(sc1.w * (float)xv[7] + sh1.w, 0.f);
    f16x8 b = *(const f16x8*)(bp + kb * 32);
    acc = __builtin_amdgcn_mfma_f32_16x16x32_f16(a, b, acc, 0, 0, 0);
  }

  float b1 = att1_b[am], w2 = att2_w[am], b2 = att2_b[0];
#pragma unroll
  for (int r = 0; r < 4; r++) {
    float t = w2 * fmaxf(acc[r] + b1, 0.f);
#pragma unroll
    for (int o = 1; o < 16; o <<= 1) t += __shfl_xor(t, o, 64);
    if (am == 0) gate_raw[nb + quad * 4 + r] = 1.f / (1.f + __expf(-(t + b2)));
  }
}

// ---------------- K7: weighted pool partials w/ inline gate softmax ----------
__global__ __launch_bounds__(256) void k_poolp(const __half* __restrict__ x2h,
                                               const float* __restrict__ gate_raw,
                                               const int* __restrict__ gcnt,
                                               const int* __restrict__ goff,
                                               const float* __restrict__ scale_g,
                                               const float* __restrict__ shift_g,
                                               float* __restrict__ ppool) {
  __shared__ float s_w[1024];
  __shared__ float red[4];
  int b = blockIdx.x, c = threadIdx.x, lane = c & 63, wid = c >> 6;
  int g = b >> 3, s = b & 7;
  int cnt = gcnt[g], start = goff[g];
  float ls = 0.f;
  for (int i = c; i < cnt; i += 256) {
    float e = __expf(gate_raw[start + i]);
    s_w[i] = e;
    ls += e;
  }
#pragma unroll
  for (int o = 32; o >= 1; o >>= 1) ls += __shfl_xor(ls, o, 64);
  if (lane == 0) red[wid] = ls;
  __syncthreads();
  float rden = 1.f / (red[0] + red[1] + red[2] + red[3] + 1e-16f);

  float sc = scale_g[g * 256 + c], sh = shift_g[g * 256 + c];
  const __half* p = x2h + (size_t)start * 256 + c;
  float pooled = 0.f;
  int i = s;
  for (; i + 56 < cnt; i += 64) {
    float v0 = __half2float(p[(size_t)(i +  0) * 256]);
    float v1 = __half2float(p[(size_t)(i +  8) * 256]);
    float v2 = __half2float(p[(size_t)(i + 16) * 256]);
    float v3 = __half2float(p[(size_t)(i + 24) * 256]);
    float v4 = __half2float(p[(size_t)(i + 32) * 256]);
    float v5 = __half2float(p[(size_t)(i + 40) * 256]);
    float v6 = __half2float(p[(size_t)(i + 48) * 256]);
    float v7 = __half2float(p[(size_t)(i + 56) * 256]);
    pooled += s_w[i +  0] * fmaxf(sc * v0 + sh, 0.f);
    pooled += s_w[i +  8] * fmaxf(sc * v1 + sh, 0.f);
    pooled += s_w[i + 16] * fmaxf(sc * v2 + sh, 0.f);
    pooled += s_w[i + 24] * fmaxf(sc * v3 + sh, 0.f);
    pooled += s_w[i + 32] * fmaxf(sc * v4 + sh, 0.f);
    pooled += s_w[i + 40] * fmaxf(sc * v5 + sh, 0.f);
    pooled += s_w[i + 48] * fmaxf(sc * v6 + sh, 0.f);
    pooled += s_w[i + 56] * fmaxf(sc * v7 + sh, 0.f);
  }
  for (; i < cnt; i += 8)
    pooled += s_w[i] * fmaxf(sc * __half2float(p[(size_t)i * 256]) + sh, 0.f);
  ppool[b * 256 + c] = pooled * rden;
}

// ---------------- K8: reduce pool partials + fc1 + out head ------------------
__global__ __launch_bounds__(256) void k_fin(const float* __restrict__ ppool,
                                             const float* __restrict__ fc1_w,
                                             const float* __restrict__ fc1_b,
                                             const float* __restrict__ out_w,
                                             const float* __restrict__ out_b,
                                             float* __restrict__ outp) {
  __shared__ __align__(16) float pool_s[256];
  __shared__ float hred[128];
  __shared__ float red[4];
  int g = blockIdx.x, tid = threadIdx.x, lane = tid & 63, wid = tid >> 6;
  int b0 = g * SPLIT;
  float acc = 0.f;
#pragma unroll
  for (int k = 0; k < SPLIT; k++) acc += ppool[(b0 + k) * 256 + tid];
  pool_s[tid] = acc;
  __syncthreads();
  float4 psv = *(const float4*)&pool_s[4 * lane];
  for (int j0 = 0; j0 < 32; j0++) {
    int j = wid * 32 + j0;
    float4 w = *(const float4*)&fc1_w[j * 256 + 4 * lane];
    float d = w.x * psv.x + w.y * psv.y + w.z * psv.z + w.w * psv.w;
#pragma unroll
    for (int o = 32; o >= 1; o >>= 1) d += __shfl_xor(d, o, 64);
    if (lane == 0) hred[j] = fmaxf(d + fc1_b[j], 0.f) * out_w[j];
  }
  __syncthreads();
  if (tid < 128) {
    float v = hred[tid];
#pragma unroll
    for (int o = 32; o >= 1; o >>= 1) v += __shfl_xor(v, o, 64);
    if (lane == 0) red[wid] = v;
  }
  __syncthreads();
  if (tid == 0) outp[g] = 1.f / (1.f + __expf(-(red[0] + red[1] + out_b[0])));
}

// -----------------------------------------------------------------------------
extern "C" void kernel_launch(void* const* d_in, const int* in_sizes, int n_in,
                              void* d_out, int out_size, void* d_ws, size_t ws_size,
                              hipStream_t stream) {
  const float* x        = (const float*)d_in[0];
  const int*   ei       = (const int*)d_in[1];
  const int*   batch    = (const int*)d_in[2];
  const float* lin_w    = (const float*)d_in[3];
  const float* att_src  = (const float*)d_in[4];
  const float* att_dst  = (const float*)d_in[5];
  const float* gat_bias = (const float*)d_in[6];
  const float* gn_w     = (const float*)d_in[7];
  const float* gn_b     = (const float*)d_in[8];
  const float* gn_ms    = (const float*)d_in[9];
  const float* fc1_w    = (const float*)d_in[10];
  const float* fc1_b    = (const float*)d_in[11];
  const float* out_w    = (const float*)d_in[12];
  const float* out_b    = (const float*)d_in[13];
  const float* att1_w   = (const float*)d_in[14];
  const float* att1_b   = (const float*)d_in[15];
  const float* att2_w   = (const float*)d_in[16];
  const float* att2_b   = (const float*)d_in[17];

  float* outp  = (float*)d_out;       // [256]
  float* alpha = outp + NG;           // [(E+N)*4]

  char* wsb = (char*)d_ws;
  size_t o = 0;
  auto A = [&](size_t bytes) -> char* {
    char* p = wsb + o;
    o += (bytes + 255) & ~(size_t)255;
    return p;
  };
  unsigned char* xh8 = (unsigned char*)A((size_t)NN * 256);
  __half*   x2h      = (__half*)A((size_t)NN * 256 * 2);
  _Float16* wh       = (_Float16*)A((size_t)256 * 64 * 2);
  _Float16* a1w      = (_Float16*)A((size_t)16 * 256 * 2);
  float* a_src_n  = (float*)A((size_t)NN * 4 * 4);
  float* a_dst_n  = (float*)A((size_t)NN * 4 * 4);
  float* den_inv  = (float*)A((size_t)NN * 4 * 4);
  float* gate_raw = (float*)A((size_t)NN * 4);
  float* psumA    = (float*)A((size_t)NG * SPLIT * 256 * 4);
  float* psumB    = (float*)A((size_t)NG * SPLIT * 256 * 4);
  float* ppool    = (float*)A((size_t)NG * SPLIT * 256 * 4);
  float* scale_g  = (float*)A((size_t)NG * 256 * 4);
  float* shift_g  = (float*)A((size_t)NG * 256 * 4);
  int*   deg      = (int*)A((size_t)NN * 4);
  int*   gcnt     = (int*)A((size_t)NG * 4);
  int*   offs     = (int*)A((size_t)NN * 4);
  int*   goff     = (int*)A((size_t)NG * 4);
  int*   src_list = (int*)A((size_t)NE * 4);
  int2*  ebuf     = (int2*)A((size_t)NB * CAP * 8);
  int*   bucket_cnt  = (int*)A((size_t)NB * 4);

  k_misc<<<21, 256, 0, stream>>>(lin_w, wh, att1_w, a1w, batch, goff, gcnt, bucket_cnt);
  k_linbin<<<NLINB + 256, 256, 0, stream>>>(x, wh, att_src, att_dst, xh8, a_src_n, a_dst_n,
                                            ei, bucket_cnt, ebuf);
  k_binB<<<NB, 256, 0, stream>>>(ebuf, bucket_cnt, deg, offs, src_list);
  k_gat<<<NN, 64, 0, stream>>>(xh8, a_src_n, a_dst_n, offs, deg, src_list,
                               gat_bias, x2h, den_inv);
  k_alst<<<ABLK + NG * SPLIT, 256, 0, stream>>>(ei, a_src_n, a_dst_n, den_inv, alpha,
                                                x2h, gcnt, goff, psumA, psumB);
  k_stats2<<<NG, 256, 0, stream>>>(psumA, psumB, gcnt, gn_w, gn_b, gn_ms, scale_g, shift_g);
  k_gate<<<(NN + 63) / 64, 256, 0, stream>>>(x2h, batch, scale_g, shift_g, a1w, att1_b,
                                             att2_w, att2_b, gate_raw);
  k_poolp<<<NG * SPLIT, 256, 0, stream>>>(x2h, gate_raw, gcnt, goff, scale_g, shift_g, ppool);
  k_fin<<<NG, 256, 0, stream>>>(ppool, fc1_w, fc1_b, out_w, out_b, outp);
}

// Round 13
// 254.717 us; speedup vs baseline: 1.0459x; 1.0459x over previous
//
#include <hip/hip_runtime.h>
#include <hip/hip_fp16.h>
#include <math.h>

#define NN 50000
#define NE 800000
#define NG 256
#define NEG_SLOPE 0.2f
#define GEPS 1e-5f
#define NB 196          // coarse buckets of 256 node-ids (dst >> 8)
#define CAP 6144        // per-bucket segment capacity (mean 4081)
#define EPB 3125        // edges per binA block (256 blocks)
#define SPLIT 8         // row-split for stats/pool partials
#define NLINB 782       // (NN+63)/64 lin blocks
#define ABLK 3321       // (NE+NN+255)/256 alpha blocks

typedef _Float16 f16x8 __attribute__((ext_vector_type(8)));
typedef _Float16 f16x4 __attribute__((ext_vector_type(4)));
typedef float f32x4 __attribute__((ext_vector_type(4)));
typedef float f32x2 __attribute__((ext_vector_type(2)));

__device__ __forceinline__ float lrelu(float v){ return v > 0.f ? v : NEG_SLOPE * v; }

// ---------------- K0: fp16 weight converts + goff + bucket_cnt zero ----------
__global__ __launch_bounds__(256) void k_misc(const float* __restrict__ lin_w,
                                              _Float16* __restrict__ wh,
                                              const float* __restrict__ att1_w,
                                              _Float16* __restrict__ a1w,
                                              const int* __restrict__ batch,
                                              int* __restrict__ goff,
                                              int* __restrict__ gcnt,
                                              int* __restrict__ bucket_cnt) {
  int b = blockIdx.x, tid = threadIdx.x;
  if (b == 0) {
    if (tid < NB) bucket_cnt[tid] = 0;
    int g = tid;
    int lo = 0, hi = NN;
    while (lo < hi) { int mid = (lo + hi) >> 1; if (batch[mid] < g) lo = mid + 1; else hi = mid; }
    int start = lo;
    lo = 0; hi = NN;
    while (lo < hi) { int mid = (lo + hi) >> 1; if (batch[mid] < g + 1) lo = mid + 1; else hi = mid; }
    goff[g] = start;
    gcnt[g] = lo - start;
  } else if (b <= 16) {
    int i0 = (b - 1) * 1024 + tid * 4;
    float4 f = *(const float4*)&lin_w[i0];
    f16x4 h4;
    h4[0] = (_Float16)f.x; h4[1] = (_Float16)f.y; h4[2] = (_Float16)f.z; h4[3] = (_Float16)f.w;
    *(f16x4*)&wh[i0] = h4;
  } else {
    int i0 = (b - 17) * 1024 + tid * 4;
    float4 f = *(const float4*)&att1_w[i0];
    f16x4 h4;
    h4[0] = (_Float16)f.x; h4[1] = (_Float16)f.y; h4[2] = (_Float16)f.z; h4[3] = (_Float16)f.w;
    *(f16x4*)&a1w[i0] = h4;
  }
}

// ---------------- K1 fused: MFMA lin (blocks < NLINB) | binA sort (rest) ------
__device__ __forceinline__ void lin_body(char* smem,
                                         const float* __restrict__ x,
                                         const _Float16* __restrict__ wh,
                                         const float* __restrict__ att_src,
                                         const float* __restrict__ att_dst,
                                         unsigned char* __restrict__ xh8,
                                         float* __restrict__ a_src_n,
                                         float* __restrict__ a_dst_n) {
  unsigned char* s_f8 = (unsigned char*)smem;     // 16 KB
  int w = threadIdx.x >> 6, lane = threadIdx.x & 63;
  int nb = blockIdx.x * 64 + w * 16;
  if (nb >= NN) return;                 // per-wave LDS region; no barriers used
  int am = lane & 15, quad = lane >> 4;
  int wb = w * 4096;

  const float* xr = x + (size_t)(nb + am) * 64 + quad * 8;
  float4 f0 = *(const float4*)(xr);
  float4 f1 = *(const float4*)(xr + 4);
  float4 f2 = *(const float4*)(xr + 32);
  float4 f3 = *(const float4*)(xr + 36);
  f16x8 a0, a1;
  a0[0] = (_Float16)f0.x; a0[1] = (_Float16)f0.y; a0[2] = (_Float16)f0.z; a0[3] = (_Float16)f0.w;
  a0[4] = (_Float16)f1.x; a0[5] = (_Float16)f1.y; a0[6] = (_Float16)f1.z; a0[7] = (_Float16)f1.w;
  a1[0] = (_Float16)f2.x; a1[1] = (_Float16)f2.y; a1[2] = (_Float16)f2.z; a1[3] = (_Float16)f2.w;
  a1[4] = (_Float16)f3.x; a1[5] = (_Float16)f3.y; a1[6] = (_Float16)f3.z; a1[7] = (_Float16)f3.w;

  f32x4 acc[16];
#pragma unroll
  for (int ct = 0; ct < 16; ct++) acc[ct] = (f32x4){0.f, 0.f, 0.f, 0.f};

#pragma unroll
  for (int ct = 0; ct < 16; ct++) {
    const _Float16* wbp = wh + (size_t)(ct * 16 + am) * 64 + quad * 8;
    f16x8 b0 = *(const f16x8*)(wbp);
    f16x8 b1 = *(const f16x8*)(wbp + 32);
    acc[ct] = __builtin_amdgcn_mfma_f32_16x16x32_f16(a0, b0, acc[ct], 0, 0, 0);
    acc[ct] = __builtin_amdgcn_mfma_f32_16x16x32_f16(a1, b1, acc[ct], 0, 0, 0);
  }

  float ps[4][4], pd[4][4];
#pragma unroll
  for (int r = 0; r < 4; r++)
#pragma unroll
    for (int h = 0; h < 4; h++) { ps[r][h] = 0.f; pd[r][h] = 0.f; }
#pragma unroll
  for (int ct = 0; ct < 16; ct++) {
    int c = ct * 16 + am;
    float av = att_src[c];
    float dv = att_dst[c];
    int h = ct >> 2;
#pragma unroll
    for (int r = 0; r < 4; r++) {
      float v = acc[ct][r];
      ps[r][h] += v * av;
      pd[r][h] += v * dv;
    }
  }
#pragma unroll
  for (int r = 0; r < 4; r++)
#pragma unroll
    for (int h = 0; h < 4; h++) {
      float s = ps[r][h], d = pd[r][h];
#pragma unroll
      for (int o = 1; o < 16; o <<= 1) {
        s += __shfl_xor(s, o, 64);
        d += __shfl_xor(d, o, 64);
      }
      if (am == 0) {
        int node = nb + quad * 4 + r;
        a_src_n[node * 4 + h] = s;
        a_dst_n[node * 4 + h] = d;
      }
    }

#pragma unroll
  for (int r = 0; r < 4; r++) {
    uint4 u;
    int t;
    t = __builtin_amdgcn_cvt_pk_fp8_f32(acc[0][r],  acc[1][r],  0, 0);
    t = __builtin_amdgcn_cvt_pk_fp8_f32(acc[2][r],  acc[3][r],  t, 1);
    u.x = (unsigned)t;
    t = __builtin_amdgcn_cvt_pk_fp8_f32(acc[4][r],  acc[5][r],  0, 0);
    t = __builtin_amdgcn_cvt_pk_fp8_f32(acc[6][r],  acc[7][r],  t, 1);
    u.y = (unsigned)t;
    t = __builtin_amdgcn_cvt_pk_fp8_f32(acc[8][r],  acc[9][r],  0, 0);
    t = __builtin_amdgcn_cvt_pk_fp8_f32(acc[10][r], acc[11][r], t, 1);
    u.z = (unsigned)t;
    t = __builtin_amdgcn_cvt_pk_fp8_f32(acc[12][r], acc[13][r], 0, 0);
    t = __builtin_amdgcn_cvt_pk_fp8_f32(acc[14][r], acc[15][r], t, 1);
    u.w = (unsigned)t;
    *(uint4*)&s_f8[wb + (quad * 4 + r) * 256 + am * 16] = u;
  }
#pragma unroll
  for (int p = 0; p < 4; p++) {
    uint4 u = *(const uint4*)&s_f8[wb + p * 1024 + lane * 16];
    *(uint4*)&xh8[(size_t)nb * 256 + p * 1024 + lane * 16] = u;
  }
}

__device__ __forceinline__ void binA_body(char* smem, int b,
                                          const int* __restrict__ ei,
                                          int* __restrict__ bucket_cnt,
                                          int2* __restrict__ ebuf) {
  int2* sorted = (int2*)smem;                         // 25000 B
  int*  hist   = (int*)(smem + 25024);
  int*  lbase  = (int*)(smem + 25824);
  int*  cur    = (int*)(smem + 26624);
  int*  runb   = (int*)(smem + 27424);
  int*  wsum   = (int*)(smem + 28224);
  int tid = threadIdx.x, lane = tid & 63, wid = tid >> 6;
  int e0 = b * EPB, e1 = min(e0 + EPB, NE);
  int n = e1 - e0;
  for (int i = tid; i < NB; i += 256) hist[i] = 0;
  __syncthreads();
  for (int e = e0 + tid; e < e1; e += 256) atomicAdd(&hist[ei[NE + e] >> 8], 1);
  __syncthreads();
  {
    int v = (tid < NB) ? hist[tid] : 0;
    int s = v;
#pragma unroll
    for (int o = 1; o < 64; o <<= 1) { int t = __shfl_up(s, o, 64); if (lane >= o) s += t; }
    if (lane == 63) wsum[wid] = s;
    __syncthreads();
    int wbase = 0;
    for (int k = 0; k < wid; k++) wbase += wsum[k];
    if (tid < NB) {
      int ex = wbase + s - v;
      lbase[tid] = ex;
      cur[tid] = ex;
      runb[tid] = atomicAdd(&bucket_cnt[tid], v);
    }
  }
  __syncthreads();
  for (int e = e0 + tid; e < e1; e += 256) {
    int d = ei[NE + e], s = ei[e];
    int lp = atomicAdd(&cur[d >> 8], 1);
    sorted[lp] = make_int2(d, s);
  }
  __syncthreads();
  for (int i = tid; i < n; i += 256) {
    int2 e = sorted[i];
    int bk = e.x >> 8;
    int slot = runb[bk] + (i - lbase[bk]);
    if (slot < CAP) ebuf[(size_t)bk * CAP + slot] = e;
  }
}

__global__ __launch_bounds__(256) void k_linbin(const float* __restrict__ x,
                                                const _Float16* __restrict__ wh,
                                                const float* __restrict__ att_src,
                                                const float* __restrict__ att_dst,
                                                unsigned char* __restrict__ xh8,
                                                float* __restrict__ a_src_n,
                                                float* __restrict__ a_dst_n,
                                                const int* __restrict__ ei,
                                                int* __restrict__ bucket_cnt,
                                                int2* __restrict__ ebuf) {
  __shared__ __align__(16) char smem[28240];
  if (blockIdx.x < NLINB)
    lin_body(smem, x, wh, att_src, att_dst, xh8, a_src_n, a_dst_n);
  else
    binA_body(smem, blockIdx.x - NLINB, ei, bucket_cnt, ebuf);
}

// ---------------- K2: per-bucket local hist+scan+scatter (inline bscan) -------
__global__ __launch_bounds__(256) void k_binB(const int2* __restrict__ ebuf,
                                              const int* __restrict__ bucket_cnt,
                                              int* __restrict__ deg,
                                              int* __restrict__ offs,
                                              int* __restrict__ src_list) {
  __shared__ int hist[256];
  __shared__ int cur[256];
  __shared__ int wsum[4];
  __shared__ int bbase[NB];
  int b = blockIdx.x, tid = threadIdx.x, lane = tid & 63, wid = tid >> 6;
  {
    int v = (tid < NB) ? min(bucket_cnt[tid], CAP) : 0;
    int s = v;
#pragma unroll
    for (int o = 1; o < 64; o <<= 1) { int t = __shfl_up(s, o, 64); if (lane >= o) s += t; }
    if (lane == 63) wsum[wid] = s;
    __syncthreads();
    int wbase = 0;
    for (int k = 0; k < wid; k++) wbase += wsum[k];
    if (tid < NB) bbase[tid] = wbase + s - v;
  }
  __syncthreads();
  int cnt = min(bucket_cnt[b], CAP);
  int base = bbase[b];
  const int2* seg = ebuf + (size_t)b * CAP;
  hist[tid] = 0;
  __syncthreads();
  for (int i = tid; i < cnt; i += 256) atomicAdd(&hist[seg[i].x & 255], 1);
  __syncthreads();
  int v = hist[tid];
  int s = v;
#pragma unroll
  for (int o = 1; o < 64; o <<= 1) { int t = __shfl_up(s, o, 64); if (lane >= o) s += t; }
  if (lane == 63) wsum[wid] = s;
  __syncthreads();
  int wbase = 0;
  for (int k = 0; k < wid; k++) wbase += wsum[k];
  int excl = wbase + s - v;
  int node = b * 256 + tid;
  if (node < NN) {
    deg[node] = v;
    offs[node] = base + excl;
  }
  cur[tid] = excl;
  __syncthreads();
  for (int i = tid; i < cnt; i += 256) {
    int2 e = seg[i];
    int pos = base + atomicAdd(&cur[e.x & 255], 1);
    src_list[pos] = e.y;
  }
}

// ---------------- K3: GAT, 4 waves/block (1 node each), no barriers -----------
// Per-wave LDS regions; intra-wave ds_write->ds_read ordering is handled by
// compiler-inserted lgkmcnt waits. Softmax normalization deferred to epilogue.
__global__ __launch_bounds__(256) void k_gat(const unsigned char* __restrict__ xh8,
                                             const float* __restrict__ a_src_n,
                                             const float* __restrict__ a_dst_n,
                                             const int* __restrict__ offs,
                                             const int* __restrict__ deg_arr,
                                             const int* __restrict__ src_list,
                                             const float* __restrict__ gat_bias,
                                             __half* __restrict__ x2h,
                                             float* __restrict__ den_inv) {
  __shared__ __align__(16) float s_al[4][64 * 4];
  __shared__ int s_src[4][64];
  __shared__ __half s_tr[4][256];
  int w = threadIdx.x >> 6, lane = threadIdx.x & 63;
  int n = blockIdx.x * 4 + w;          // NN % 4 == 0
  int off = offs[n], dg = deg_arr[n], cnt = dg + 1;
  float4 ad = *(const float4*)&a_dst_n[n * 4];
  int h = lane & 3;
  unsigned loff = 4u * (unsigned)lane;

  float acc0 = 0.f, acc1 = 0.f, acc2 = 0.f, acc3 = 0.f;
  float s0 = 0.f, s1 = 0.f, s2 = 0.f, s3 = 0.f;

  for (int cb = 0; cb < cnt; cb += 64) {
    int clen = min(64, cnt - cb);
    if (lane < clen) {
      int j = cb + lane;
      int src = (j < dg) ? src_list[off + j] : n;
      float4 as = *(const float4*)&a_src_n[src * 4];
      float e0 = __expf(lrelu(as.x + ad.x));
      float e1 = __expf(lrelu(as.y + ad.y));
      float e2 = __expf(lrelu(as.z + ad.z));
      float e3 = __expf(lrelu(as.w + ad.w));
      s_src[w][lane] = src;
      *(float4*)&s_al[w][lane * 4] = make_float4(e0, e1, e2, e3);
      s0 += e0; s1 += e1; s2 += e2; s3 += e3;
    }
    int j = 0;
    for (; j + 4 <= clen; j += 4) {
      unsigned oA = ((unsigned)s_src[w][j]     << 8) + loff;
      unsigned oB = ((unsigned)s_src[w][j + 1] << 8) + loff;
      unsigned oC = ((unsigned)s_src[w][j + 2] << 8) + loff;
      unsigned oD = ((unsigned)s_src[w][j + 3] << 8) + loff;
      unsigned rA = *(const unsigned*)&xh8[oA];
      unsigned rB = *(const unsigned*)&xh8[oB];
      unsigned rC = *(const unsigned*)&xh8[oC];
      unsigned rD = *(const unsigned*)&xh8[oD];
      float aA = s_al[w][j * 4 + h],       aB = s_al[w][(j + 1) * 4 + h];
      float aC = s_al[w][(j + 2) * 4 + h], aD = s_al[w][(j + 3) * 4 + h];
      f32x2 lA = __builtin_amdgcn_cvt_pk_f32_fp8((int)rA, 0);
      f32x2 hA = __builtin_amdgcn_cvt_pk_f32_fp8((int)rA, 1);
      f32x2 lB = __builtin_amdgcn_cvt_pk_f32_fp8((int)rB, 0);
      f32x2 hB = __builtin_amdgcn_cvt_pk_f32_fp8((int)rB, 1);
      f32x2 lC = __builtin_amdgcn_cvt_pk_f32_fp8((int)rC, 0);
      f32x2 hC = __builtin_amdgcn_cvt_pk_f32_fp8((int)rC, 1);
      f32x2 lD = __builtin_amdgcn_cvt_pk_f32_fp8((int)rD, 0);
      f32x2 hD = __builtin_amdgcn_cvt_pk_f32_fp8((int)rD, 1);
      acc0 += aA * lA[0] + aB * lB[0] + aC * lC[0] + aD * lD[0];
      acc1 += aA * lA[1] + aB * lB[1] + aC * lC[1] + aD * lD[1];
      acc2 += aA * hA[0] + aB * hB[0] + aC * hC[0] + aD * hD[0];
      acc3 += aA * hA[1] + aB * hB[1] + aC * hC[1] + aD * hD[1];
    }
    for (; j < clen; j++) {
      unsigned oA = ((unsigned)s_src[w][j] << 8) + loff;
      unsigned rA = *(const unsigned*)&xh8[oA];
      float aA = s_al[w][j * 4 + h];
      f32x2 lA = __builtin_amdgcn_cvt_pk_f32_fp8((int)rA, 0);
      f32x2 hA = __builtin_amdgcn_cvt_pk_f32_fp8((int)rA, 1);
      acc0 += aA * lA[0];
      acc1 += aA * lA[1];
      acc2 += aA * hA[0];
      acc3 += aA * hA[1];
    }
  }

#pragma unroll
  for (int o = 32; o >= 1; o >>= 1) {
    s0 += __shfl_xor(s0, o, 64);
    s1 += __shfl_xor(s1, o, 64);
    s2 += __shfl_xor(s2, o, 64);
    s3 += __shfl_xor(s3, o, 64);
  }
  float i0 = 1.f / (s0 + 1e-16f), i1 = 1.f / (s1 + 1e-16f);
  float i2 = 1.f / (s2 + 1e-16f), i3 = 1.f / (s3 + 1e-16f);
  if (lane == 0) *(float4*)&den_inv[n * 4] = make_float4(i0, i1, i2, i3);

  float ivh = (h == 0) ? i0 : (h == 1) ? i1 : (h == 2) ? i2 : i3;
  int cb0 = (lane & 3) * 64 + (lane >> 2);
  s_tr[w][cb0 +  0] = __float2half(acc0 * ivh + gat_bias[cb0 +  0]);
  s_tr[w][cb0 + 16] = __float2half(acc1 * ivh + gat_bias[cb0 + 16]);
  s_tr[w][cb0 + 32] = __float2half(acc2 * ivh + gat_bias[cb0 + 32]);
  s_tr[w][cb0 + 48] = __float2half(acc3 * ivh + gat_bias[cb0 + 48]);
  uint2 u = *(const uint2*)&s_tr[w][4 * lane];
  *(uint2*)&x2h[(size_t)n * 256 + 4 * lane] = u;
}

// ---------------- K4 fused: alpha (blocks < ABLK) | stats1 partials (rest) ----
__global__ __launch_bounds__(256) void k_alst(const int* __restrict__ ei,
                                              const float* __restrict__ a_src_n,
                                              const float* __restrict__ a_dst_n,
                                              const float* __restrict__ den_inv,
                                              float* __restrict__ alpha_out,
                                              const __half* __restrict__ x2h,
                                              const int* __restrict__ gcnt,
                                              const int* __restrict__ goff,
                                              float* __restrict__ psumA,
                                              float* __restrict__ psumB) {
  if (blockIdx.x < ABLK) {
    int idx = blockIdx.x * 256 + threadIdx.x;
    if (idx >= NE + NN) return;
    int s, d;
    if (idx < NE) { s = ei[idx]; d = ei[NE + idx]; }
    else          { s = idx - NE; d = s; }
    float4 as = *(const float4*)&a_src_n[s * 4];
    float4 ad = *(const float4*)&a_dst_n[d * 4];
    float4 iv = *(const float4*)&den_inv[d * 4];
    float4 a;
    a.x = __expf(lrelu(as.x + ad.x)) * iv.x;
    a.y = __expf(lrelu(as.y + ad.y)) * iv.y;
    a.z = __expf(lrelu(as.z + ad.z)) * iv.z;
    a.w = __expf(lrelu(as.w + ad.w)) * iv.w;
    *(float4*)&alpha_out[(size_t)idx * 4] = a;
  } else {
    int b = blockIdx.x - ABLK, c = threadIdx.x;
    int g = b >> 3, s = b & 7;
    int cnt = gcnt[g], start = goff[g];
    const __half* p = x2h + (size_t)start * 256 + c;
    float sum = 0.f, sum2 = 0.f;
    int i = s;
    for (; i + 56 < cnt; i += 64) {
      float v0 = __half2float(p[(size_t)(i +  0) * 256]);
      float v1 = __half2float(p[(size_t)(i +  8) * 256]);
      float v2 = __half2float(p[(size_t)(i + 16) * 256]);
      float v3 = __half2float(p[(size_t)(i + 24) * 256]);
      float v4 = __half2float(p[(size_t)(i + 32) * 256]);
      float v5 = __half2float(p[(size_t)(i + 40) * 256]);
      float v6 = __half2float(p[(size_t)(i + 48) * 256]);
      float v7 = __half2float(p[(size_t)(i + 56) * 256]);
      sum += ((v0 + v1) + (v2 + v3)) + ((v4 + v5) + (v6 + v7));
      sum2 += ((v0 * v0 + v1 * v1) + (v2 * v2 + v3 * v3)) +
              ((v4 * v4 + v5 * v5) + (v6 * v6 + v7 * v7));
    }
    for (; i < cnt; i += 8) { float v = __half2float(p[(size_t)i * 256]); sum += v; sum2 += v * v; }
    psumA[b * 256 + c] = sum;
    psumB[b * 256 + c] = sum2;
  }
}

// ---------------- K5: finalize scale/shift -----------------------------------
__global__ __launch_bounds__(256) void k_stats2(const float* __restrict__ psumA,
                                                const float* __restrict__ psumB,
                                                const int* __restrict__ gcnt,
                                                const float* __restrict__ gn_w,
                                                const float* __restrict__ gn_b,
                                                const float* __restrict__ gn_ms,
                                                float* __restrict__ scale_g,
                                                float* __restrict__ shift_g) {
  int g = blockIdx.x, c = threadIdx.x;
  int b0 = g * SPLIT;
  float S = 0.f, S2 = 0.f;
#pragma unroll
  for (int k = 0; k < SPLIT; k++) {
    S  += psumA[(b0 + k) * 256 + c];
    S2 += psumB[(b0 + k) * 256 + c];
  }
  float fc = fmaxf((float)gcnt[g], 1.f);
  float mean = S / fc;
  float mm = mean * gn_ms[c];
  float var = fmaxf(S2 / fc - 2.f * mm * mean + mm * mm, 0.f);
  float sc = gn_w[c] / sqrtf(var + GEPS);
  scale_g[g * 256 + c] = sc;
  shift_g[g * 256 + c] = gn_b[c] - sc * mm;
}

// ---------------- K6: gate MLP via MFMA (16 nodes / wave) --------------------
__global__ __launch_bounds__(256) void k_gate(const __half* __restrict__ x2h,
                                              const int* __restrict__ batch,
                                              const float* __restrict__ scale_g,
                                              const float* __restrict__ shift_g,
                                              const _Float16* __restrict__ a1w,
                                              const float* __restrict__ att1_b,
                                              const float* __restrict__ att2_w,
                                              const float* __restrict__ att2_b,
                                              float* __restrict__ gate_raw) {
  int w = threadIdx.x >> 6, lane = threadIdx.x & 63;
  int nb = blockIdx.x * 64 + w * 16;
  if (nb >= NN) return;                 // no barriers -> safe
  int am = lane & 15, quad = lane >> 4;
  int node = nb + am;
  int g = batch[node];

  const __half*   xp  = x2h + (size_t)node * 256 + quad * 8;
  const float*    scp = scale_g + g * 256 + quad * 8;
  const float*    shp = shift_g + g * 256 + quad * 8;
  const _Float16* bp  = a1w + am * 256 + quad * 8;

  f32x4 acc = (f32x4){0.f, 0.f, 0.f, 0.f};
#pragma unroll
  for (int kb = 0; kb < 8; kb++) {
    f16x8 xv = *(const f16x8*)(xp + kb * 32);
    float4 sc0 = *(const float4*)(scp + kb * 32);
    float4 sc1 = *(const float4*)(scp + kb * 32 + 4);
    float4 sh0 = *(const float4*)(shp + kb * 32);
    float4 sh1 = *(const float4*)(shp + kb * 32 + 4);
    f16x8 a;
    a[0] = (_Float16)fmaxf(sc0.x * (float)xv[0] + sh0.x, 0.f);
    a[1] = (_Float16)fmaxf(sc0.y * (float)xv[1] + sh0.y, 0.f);
    a[2] = (_Float16)fmaxf(sc0.z * (float)xv[2] + sh0.z, 0.f);
    a[3] = (_Float16)fmaxf(sc0.w * (float)xv[3] + sh0.w, 0.f);
    a[4] = (_Float16)fmaxf(sc1.x * (float)xv[4] + sh1.x, 0.f);
    a[5] = (_Float16)fmaxf(sc1.y * (float)xv[5] + sh1.y, 0.f);
    a[6] = (_Float16)fmaxf(sc1.z * (float)xv[6] + sh1.z, 0.f);
    a[7] = (_Float16)fmaxf(sc1.w * (float)xv[7] + sh1.w, 0.f);
    f16x8 b = *(const f16x8*)(bp + kb * 32);
    acc = __builtin_amdgcn_mfma_f32_16x16x32_f16(a, b, acc, 0, 0, 0);
  }

  float b1 = att1_b[am], w2 = att2_w[am], b2 = att2_b[0];
#pragma unroll
  for (int r = 0; r < 4; r++) {
    float t = w2 * fmaxf(acc[r] + b1, 0.f);
#pragma unroll
    for (int o = 1; o < 16; o <<= 1) t += __shfl_xor(t, o, 64);
    if (am == 0) gate_raw[nb + quad * 4 + r] = 1.f / (1.f + __expf(-(t + b2)));
  }
}

// ---------------- K7: weighted pool partials w/ inline gate softmax ----------
__global__ __launch_bounds__(256) void k_poolp(const __half* __restrict__ x2h,
                                               const float* __restrict__ gate_raw,
                                               const int* __restrict__ gcnt,
                                               const int* __restrict__ goff,
                                               const float* __restrict__ scale_g,
                                               const float* __restrict__ shift_g,
                                               float* __restrict__ ppool) {
  __shared__ float s_w[1024];
  __shared__ float red[4];
  int b = blockIdx.x, c = threadIdx.x, lane = c & 63, wid = c >> 6;
  int g = b >> 3, s = b & 7;
  int cnt = gcnt[g], start = goff[g];
  float ls = 0.f;
  for (int i = c; i < cnt; i += 256) {
    float e = __expf(gate_raw[start + i]);
    s_w[i] = e;
    ls += e;
  }
#pragma unroll
  for (int o = 32; o >= 1; o >>= 1) ls += __shfl_xor(ls, o, 64);
  if (lane == 0) red[wid] = ls;
  __syncthreads();
  float rden = 1.f / (red[0] + red[1] + red[2] + red[3] + 1e-16f);

  float sc = scale_g[g * 256 + c], sh = shift_g[g * 256 + c];
  const __half* p = x2h + (size_t)start * 256 + c;
  float pooled = 0.f;
  int i = s;
  for (; i + 56 < cnt; i += 64) {
    float v0 = __half2float(p[(size_t)(i +  0) * 256]);
    float v1 = __half2float(p[(size_t)(i +  8) * 256]);
    float v2 = __half2float(p[(size_t)(i + 16) * 256]);
    float v3 = __half2float(p[(size_t)(i + 24) * 256]);
    float v4 = __half2float(p[(size_t)(i + 32) * 256]);
    float v5 = __half2float(p[(size_t)(i + 40) * 256]);
    float v6 = __half2float(p[(size_t)(i + 48) * 256]);
    float v7 = __half2float(p[(size_t)(i + 56) * 256]);
    pooled += s_w[i +  0] * fmaxf(sc * v0 + sh, 0.f);
    pooled += s_w[i +  8] * fmaxf(sc * v1 + sh, 0.f);
    pooled += s_w[i + 16] * fmaxf(sc * v2 + sh, 0.f);
    pooled += s_w[i + 24] * fmaxf(sc * v3 + sh, 0.f);
    pooled += s_w[i + 32] * fmaxf(sc * v4 + sh, 0.f);
    pooled += s_w[i + 40] * fmaxf(sc * v5 + sh, 0.f);
    pooled += s_w[i + 48] * fmaxf(sc * v6 + sh, 0.f);
    pooled += s_w[i + 56] * fmaxf(sc * v7 + sh, 0.f);
  }
  for (; i < cnt; i += 8)
    pooled += s_w[i] * fmaxf(sc * __half2float(p[(size_t)i * 256]) + sh, 0.f);
  ppool[b * 256 + c] = pooled * rden;
}

// ---------------- K8: reduce pool partials + fc1 + out head ------------------
__global__ __launch_bounds__(256) void k_fin(const float* __restrict__ ppool,
                                             const float* __restrict__ fc1_w,
                                             const float* __restrict__ fc1_b,
                                             const float* __restrict__ out_w,
                                             const float* __restrict__ out_b,
                                             float* __restrict__ outp) {
  __shared__ __align__(16) float pool_s[256];
  __shared__ float hred[128];
  __shared__ float red[4];
  int g = blockIdx.x, tid = threadIdx.x, lane = tid & 63, wid = tid >> 6;
  int b0 = g * SPLIT;
  float acc = 0.f;
#pragma unroll
  for (int k = 0; k < SPLIT; k++) acc += ppool[(b0 + k) * 256 + tid];
  pool_s[tid] = acc;
  __syncthreads();
  float4 psv = *(const float4*)&pool_s[4 * lane];
  for (int j0 = 0; j0 < 32; j0++) {
    int j = wid * 32 + j0;
    float4 w = *(const float4*)&fc1_w[j * 256 + 4 * lane];
    float d = w.x * psv.x + w.y * psv.y + w.z * psv.z + w.w * psv.w;
#pragma unroll
    for (int o = 32; o >= 1; o >>= 1) d += __shfl_xor(d, o, 64);
    if (lane == 0) hred[j] = fmaxf(d + fc1_b[j], 0.f) * out_w[j];
  }
  __syncthreads();
  if (tid < 128) {
    float v = hred[tid];
#pragma unroll
    for (int o = 32; o >= 1; o >>= 1) v += __shfl_xor(v, o, 64);
    if (lane == 0) red[wid] = v;
  }
  __syncthreads();
  if (tid == 0) outp[g] = 1.f / (1.f + __expf(-(red[0] + red[1] + out_b[0])));
}

// -----------------------------------------------------------------------------
extern "C" void kernel_launch(void* const* d_in, const int* in_sizes, int n_in,
                              void* d_out, int out_size, void* d_ws, size_t ws_size,
                              hipStream_t stream) {
  const float* x        = (const float*)d_in[0];
  const int*   ei       = (const int*)d_in[1];
  const int*   batch    = (const int*)d_in[2];
  const float* lin_w    = (const float*)d_in[3];
  const float* att_src  = (const float*)d_in[4];
  const float* att_dst  = (const float*)d_in[5];
  const float* gat_bias = (const float*)d_in[6];
  const float* gn_w     = (const float*)d_in[7];
  const float* gn_b     = (const float*)d_in[8];
  const float* gn_ms    = (const float*)d_in[9];
  const float* fc1_w    = (const float*)d_in[10];
  const float* fc1_b    = (const float*)d_in[11];
  const float* out_w    = (const float*)d_in[12];
  const float* out_b    = (const float*)d_in[13];
  const float* att1_w   = (const float*)d_in[14];
  const float* att1_b   = (const float*)d_in[15];
  const float* att2_w   = (const float*)d_in[16];
  const float* att2_b   = (const float*)d_in[17];

  float* outp  = (float*)d_out;       // [256]
  float* alpha = outp + NG;           // [(E+N)*4]

  char* wsb = (char*)d_ws;
  size_t o = 0;
  auto A = [&](size_t bytes) -> char* {
    char* p = wsb + o;
    o += (bytes + 255) & ~(size_t)255;
    return p;
  };
  unsigned char* xh8 = (unsigned char*)A((size_t)NN * 256);
  __half*   x2h      = (__half*)A((size_t)NN * 256 * 2);
  _Float16* wh       = (_Float16*)A((size_t)256 * 64 * 2);
  _Float16* a1w      = (_Float16*)A((size_t)16 * 256 * 2);
  float* a_src_n  = (float*)A((size_t)NN * 4 * 4);
  float* a_dst_n  = (float*)A((size_t)NN * 4 * 4);
  float* den_inv  = (float*)A((size_t)NN * 4 * 4);
  float* gate_raw = (float*)A((size_t)NN * 4);
  float* psumA    = (float*)A((size_t)NG * SPLIT * 256 * 4);
  float* psumB    = (float*)A((size_t)NG * SPLIT * 256 * 4);
  float* ppool    = (float*)A((size_t)NG * SPLIT * 256 * 4);
  float* scale_g  = (float*)A((size_t)NG * 256 * 4);
  float* shift_g  = (float*)A((size_t)NG * 256 * 4);
  int*   deg      = (int*)A((size_t)NN * 4);
  int*   gcnt     = (int*)A((size_t)NG * 4);
  int*   offs     = (int*)A((size_t)NN * 4);
  int*   goff     = (int*)A((size_t)NG * 4);
  int*   src_list = (int*)A((size_t)NE * 4);
  int2*  ebuf     = (int2*)A((size_t)NB * CAP * 8);
  int*   bucket_cnt  = (int*)A((size_t)NB * 4);

  k_misc<<<21, 256, 0, stream>>>(lin_w, wh, att1_w, a1w, batch, goff, gcnt, bucket_cnt);
  k_linbin<<<NLINB + 256, 256, 0, stream>>>(x, wh, att_src, att_dst, xh8, a_src_n, a_dst_n,
                                            ei, bucket_cnt, ebuf);
  k_binB<<<NB, 256, 0, stream>>>(ebuf, bucket_cnt, deg, offs, src_list);
  k_gat<<<NN / 4, 256, 0, stream>>>(xh8, a_src_n, a_dst_n, offs, deg, src_list,
                                    gat_bias, x2h, den_inv);
  k_alst<<<ABLK + NG * SPLIT, 256, 0, stream>>>(ei, a_src_n, a_dst_n, den_inv, alpha,
                                                x2h, gcnt, goff, psumA, psumB);
  k_stats2<<<NG, 256, 0, stream>>>(psumA, psumB, gcnt, gn_w, gn_b, gn_ms, scale_g, shift_g);
  k_gate<<<(NN + 63) / 64, 256, 0, stream>>>(x2h, batch, scale_g, shift_g, a1w, att1_b,
                                             att2_w, att2_b, gate_raw);
  k_poolp<<<NG * SPLIT, 256, 0, stream>>>(x2h, gate_raw, gcnt, goff, scale_g, shift_g, ppool);
  k_fin<<<NG, 256, 0, stream>>>(ppool, fc1_w, fc1_b, out_w, out_b, outp);
}

// Round 14
// 251.168 us; speedup vs baseline: 1.0607x; 1.0141x over previous
//
#include <hip/hip_runtime.h>
#include <hip/hip_fp16.h>
#include <math.h>

#define NN 50000
#define NE 800000
#define NG 256
#define NEG_SLOPE 0.2f
#define GEPS 1e-5f
#define NB 196          // coarse buckets of 256 node-ids (dst >> 8)
#define CAP 6144        // per-bucket segment capacity (mean 4081)
#define EPB 3125        // edges per binA block (256 blocks)
#define SPLIT 8         // row-split for stats/pool partials
#define NLINB 782       // (NN+63)/64 lin blocks
#define ABLK 3321       // (NE+NN+255)/256 alpha blocks

typedef _Float16 f16x8 __attribute__((ext_vector_type(8)));
typedef _Float16 f16x4 __attribute__((ext_vector_type(4)));
typedef float f32x4 __attribute__((ext_vector_type(4)));
typedef float f32x2 __attribute__((ext_vector_type(2)));

__device__ __forceinline__ float lrelu(float v){ return v > 0.f ? v : NEG_SLOPE * v; }

// ---------------- K0: fp16 weight converts + goff + bucket_cnt zero ----------
__global__ __launch_bounds__(256) void k_misc(const float* __restrict__ lin_w,
                                              _Float16* __restrict__ wh,
                                              const float* __restrict__ att1_w,
                                              _Float16* __restrict__ a1w,
                                              const int* __restrict__ batch,
                                              int* __restrict__ goff,
                                              int* __restrict__ gcnt,
                                              int* __restrict__ bucket_cnt) {
  int b = blockIdx.x, tid = threadIdx.x;
  if (b == 0) {
    if (tid < NB) bucket_cnt[tid] = 0;
    int g = tid;
    int lo = 0, hi = NN;
    while (lo < hi) { int mid = (lo + hi) >> 1; if (batch[mid] < g) lo = mid + 1; else hi = mid; }
    int start = lo;
    lo = 0; hi = NN;
    while (lo < hi) { int mid = (lo + hi) >> 1; if (batch[mid] < g + 1) lo = mid + 1; else hi = mid; }
    goff[g] = start;
    gcnt[g] = lo - start;
  } else if (b <= 16) {
    int i0 = (b - 1) * 1024 + tid * 4;
    float4 f = *(const float4*)&lin_w[i0];
    f16x4 h4;
    h4[0] = (_Float16)f.x; h4[1] = (_Float16)f.y; h4[2] = (_Float16)f.z; h4[3] = (_Float16)f.w;
    *(f16x4*)&wh[i0] = h4;
  } else {
    int i0 = (b - 17) * 1024 + tid * 4;
    float4 f = *(const float4*)&att1_w[i0];
    f16x4 h4;
    h4[0] = (_Float16)f.x; h4[1] = (_Float16)f.y; h4[2] = (_Float16)f.z; h4[3] = (_Float16)f.w;
    *(f16x4*)&a1w[i0] = h4;
  }
}

// ---------------- K1 fused: MFMA lin (blocks < NLINB) | binA sort (rest) ------
__device__ __forceinline__ void lin_body(char* smem,
                                         const float* __restrict__ x,
                                         const _Float16* __restrict__ wh,
                                         const float* __restrict__ att_src,
                                         const float* __restrict__ att_dst,
                                         unsigned char* __restrict__ xh8,
                                         float* __restrict__ a_src_n,
                                         float* __restrict__ a_dst_n) {
  unsigned char* s_f8 = (unsigned char*)smem;     // 16 KB
  int w = threadIdx.x >> 6, lane = threadIdx.x & 63;
  int nb = blockIdx.x * 64 + w * 16;
  if (nb >= NN) return;                 // per-wave LDS region; no barriers used
  int am = lane & 15, quad = lane >> 4;
  int wb = w * 4096;

  const float* xr = x + (size_t)(nb + am) * 64 + quad * 8;
  float4 f0 = *(const float4*)(xr);
  float4 f1 = *(const float4*)(xr + 4);
  float4 f2 = *(const float4*)(xr + 32);
  float4 f3 = *(const float4*)(xr + 36);
  f16x8 a0, a1;
  a0[0] = (_Float16)f0.x; a0[1] = (_Float16)f0.y; a0[2] = (_Float16)f0.z; a0[3] = (_Float16)f0.w;
  a0[4] = (_Float16)f1.x; a0[5] = (_Float16)f1.y; a0[6] = (_Float16)f1.z; a0[7] = (_Float16)f1.w;
  a1[0] = (_Float16)f2.x; a1[1] = (_Float16)f2.y; a1[2] = (_Float16)f2.z; a1[3] = (_Float16)f2.w;
  a1[4] = (_Float16)f3.x; a1[5] = (_Float16)f3.y; a1[6] = (_Float16)f3.z; a1[7] = (_Float16)f3.w;

  f32x4 acc[16];
#pragma unroll
  for (int ct = 0; ct < 16; ct++) acc[ct] = (f32x4){0.f, 0.f, 0.f, 0.f};

#pragma unroll
  for (int ct = 0; ct < 16; ct++) {
    const _Float16* wbp = wh + (size_t)(ct * 16 + am) * 64 + quad * 8;
    f16x8 b0 = *(const f16x8*)(wbp);
    f16x8 b1 = *(const f16x8*)(wbp + 32);
    acc[ct] = __builtin_amdgcn_mfma_f32_16x16x32_f16(a0, b0, acc[ct], 0, 0, 0);
    acc[ct] = __builtin_amdgcn_mfma_f32_16x16x32_f16(a1, b1, acc[ct], 0, 0, 0);
  }

  float ps[4][4], pd[4][4];
#pragma unroll
  for (int r = 0; r < 4; r++)
#pragma unroll
    for (int h = 0; h < 4; h++) { ps[r][h] = 0.f; pd[r][h] = 0.f; }
#pragma unroll
  for (int ct = 0; ct < 16; ct++) {
    int c = ct * 16 + am;
    float av = att_src[c];
    float dv = att_dst[c];
    int h = ct >> 2;
#pragma unroll
    for (int r = 0; r < 4; r++) {
      float v = acc[ct][r];
      ps[r][h] += v * av;
      pd[r][h] += v * dv;
    }
  }
#pragma unroll
  for (int r = 0; r < 4; r++)
#pragma unroll
    for (int h = 0; h < 4; h++) {
      float s = ps[r][h], d = pd[r][h];
#pragma unroll
      for (int o = 1; o < 16; o <<= 1) {
        s += __shfl_xor(s, o, 64);
        d += __shfl_xor(d, o, 64);
      }
      if (am == 0) {
        int node = nb + quad * 4 + r;
        a_src_n[node * 4 + h] = s;
        a_dst_n[node * 4 + h] = d;
      }
    }

#pragma unroll
  for (int r = 0; r < 4; r++) {
    uint4 u;
    int t;
    t = __builtin_amdgcn_cvt_pk_fp8_f32(acc[0][r],  acc[1][r],  0, 0);
    t = __builtin_amdgcn_cvt_pk_fp8_f32(acc[2][r],  acc[3][r],  t, 1);
    u.x = (unsigned)t;
    t = __builtin_amdgcn_cvt_pk_fp8_f32(acc[4][r],  acc[5][r],  0, 0);
    t = __builtin_amdgcn_cvt_pk_fp8_f32(acc[6][r],  acc[7][r],  t, 1);
    u.y = (unsigned)t;
    t = __builtin_amdgcn_cvt_pk_fp8_f32(acc[8][r],  acc[9][r],  0, 0);
    t = __builtin_amdgcn_cvt_pk_fp8_f32(acc[10][r], acc[11][r], t, 1);
    u.z = (unsigned)t;
    t = __builtin_amdgcn_cvt_pk_fp8_f32(acc[12][r], acc[13][r], 0, 0);
    t = __builtin_amdgcn_cvt_pk_fp8_f32(acc[14][r], acc[15][r], t, 1);
    u.w = (unsigned)t;
    *(uint4*)&s_f8[wb + (quad * 4 + r) * 256 + am * 16] = u;
  }
#pragma unroll
  for (int p = 0; p < 4; p++) {
    uint4 u = *(const uint4*)&s_f8[wb + p * 1024 + lane * 16];
    *(uint4*)&xh8[(size_t)nb * 256 + p * 1024 + lane * 16] = u;
  }
}

__device__ __forceinline__ void binA_body(char* smem, int b,
                                          const int* __restrict__ ei,
                                          int* __restrict__ bucket_cnt,
                                          int2* __restrict__ ebuf) {
  int2* sorted = (int2*)smem;                         // 25000 B
  int*  hist   = (int*)(smem + 25024);
  int*  lbase  = (int*)(smem + 25824);
  int*  cur    = (int*)(smem + 26624);
  int*  runb   = (int*)(smem + 27424);
  int*  wsum   = (int*)(smem + 28224);
  int tid = threadIdx.x, lane = tid & 63, wid = tid >> 6;
  int e0 = b * EPB, e1 = min(e0 + EPB, NE);
  int n = e1 - e0;
  for (int i = tid; i < NB; i += 256) hist[i] = 0;
  __syncthreads();
  for (int e = e0 + tid; e < e1; e += 256) atomicAdd(&hist[ei[NE + e] >> 8], 1);
  __syncthreads();
  {
    int v = (tid < NB) ? hist[tid] : 0;
    int s = v;
#pragma unroll
    for (int o = 1; o < 64; o <<= 1) { int t = __shfl_up(s, o, 64); if (lane >= o) s += t; }
    if (lane == 63) wsum[wid] = s;
    __syncthreads();
    int wbase = 0;
    for (int k = 0; k < wid; k++) wbase += wsum[k];
    if (tid < NB) {
      int ex = wbase + s - v;
      lbase[tid] = ex;
      cur[tid] = ex;
      runb[tid] = atomicAdd(&bucket_cnt[tid], v);
    }
  }
  __syncthreads();
  for (int e = e0 + tid; e < e1; e += 256) {
    int d = ei[NE + e], s = ei[e];
    int lp = atomicAdd(&cur[d >> 8], 1);
    sorted[lp] = make_int2(d, s);
  }
  __syncthreads();
  for (int i = tid; i < n; i += 256) {
    int2 e = sorted[i];
    int bk = e.x >> 8;
    int slot = runb[bk] + (i - lbase[bk]);
    if (slot < CAP) ebuf[(size_t)bk * CAP + slot] = e;
  }
}

__global__ __launch_bounds__(256) void k_linbin(const float* __restrict__ x,
                                                const _Float16* __restrict__ wh,
                                                const float* __restrict__ att_src,
                                                const float* __restrict__ att_dst,
                                                unsigned char* __restrict__ xh8,
                                                float* __restrict__ a_src_n,
                                                float* __restrict__ a_dst_n,
                                                const int* __restrict__ ei,
                                                int* __restrict__ bucket_cnt,
                                                int2* __restrict__ ebuf) {
  __shared__ __align__(16) char smem[28240];
  if (blockIdx.x < NLINB)
    lin_body(smem, x, wh, att_src, att_dst, xh8, a_src_n, a_dst_n);
  else
    binA_body(smem, blockIdx.x - NLINB, ei, bucket_cnt, ebuf);
}

// ---------------- K2: per-bucket local hist+scan+scatter (inline bscan) -------
__global__ __launch_bounds__(256) void k_binB(const int2* __restrict__ ebuf,
                                              const int* __restrict__ bucket_cnt,
                                              int* __restrict__ deg,
                                              int* __restrict__ offs,
                                              int* __restrict__ src_list) {
  __shared__ int hist[256];
  __shared__ int cur[256];
  __shared__ int wsum[4];
  __shared__ int bbase[NB];
  int b = blockIdx.x, tid = threadIdx.x, lane = tid & 63, wid = tid >> 6;
  {
    int v = (tid < NB) ? min(bucket_cnt[tid], CAP) : 0;
    int s = v;
#pragma unroll
    for (int o = 1; o < 64; o <<= 1) { int t = __shfl_up(s, o, 64); if (lane >= o) s += t; }
    if (lane == 63) wsum[wid] = s;
    __syncthreads();
    int wbase = 0;
    for (int k = 0; k < wid; k++) wbase += wsum[k];
    if (tid < NB) bbase[tid] = wbase + s - v;
  }
  __syncthreads();
  int cnt = min(bucket_cnt[b], CAP);
  int base = bbase[b];
  const int2* seg = ebuf + (size_t)b * CAP;
  hist[tid] = 0;
  __syncthreads();
  for (int i = tid; i < cnt; i += 256) atomicAdd(&hist[seg[i].x & 255], 1);
  __syncthreads();
  int v = hist[tid];
  int s = v;
#pragma unroll
  for (int o = 1; o < 64; o <<= 1) { int t = __shfl_up(s, o, 64); if (lane >= o) s += t; }
  if (lane == 63) wsum[wid] = s;
  __syncthreads();
  int wbase = 0;
  for (int k = 0; k < wid; k++) wbase += wsum[k];
  int excl = wbase + s - v;
  int node = b * 256 + tid;
  if (node < NN) {
    deg[node] = v;
    offs[node] = base + excl;
  }
  cur[tid] = excl;
  __syncthreads();
  for (int i = tid; i < cnt; i += 256) {
    int2 e = seg[i];
    int pos = base + atomicAdd(&cur[e.x & 255], 1);
    src_list[pos] = e.y;
  }
}

// ---------------- K3: GAT, one wave/node, single pass, deferred norm ----------
__global__ __launch_bounds__(64) void k_gat(const unsigned char* __restrict__ xh8,
                                            const float* __restrict__ a_src_n,
                                            const float* __restrict__ a_dst_n,
                                            const int* __restrict__ offs,
                                            const int* __restrict__ deg_arr,
                                            const int* __restrict__ src_list,
                                            const float* __restrict__ gat_bias,
                                            __half* __restrict__ x2h,
                                            float* __restrict__ den_inv) {
  __shared__ __align__(16) float s_al[64 * 4];
  __shared__ int s_src[64];
  __shared__ __half s_tr[256];
  int n = blockIdx.x, lane = threadIdx.x;
  int off = offs[n], dg = deg_arr[n], cnt = dg + 1;
  float4 ad = *(const float4*)&a_dst_n[n * 4];
  int h = lane & 3;
  unsigned loff = 4u * (unsigned)lane;

  float acc0 = 0.f, acc1 = 0.f, acc2 = 0.f, acc3 = 0.f;
  float s0 = 0.f, s1 = 0.f, s2 = 0.f, s3 = 0.f;

  for (int cb = 0; cb < cnt; cb += 64) {
    int clen = min(64, cnt - cb);
    if (lane < clen) {
      int j = cb + lane;
      int src = (j < dg) ? src_list[off + j] : n;
      float4 as = *(const float4*)&a_src_n[src * 4];
      float e0 = __expf(lrelu(as.x + ad.x));
      float e1 = __expf(lrelu(as.y + ad.y));
      float e2 = __expf(lrelu(as.z + ad.z));
      float e3 = __expf(lrelu(as.w + ad.w));
      s_src[lane] = src;
      *(float4*)&s_al[lane * 4] = make_float4(e0, e1, e2, e3);
      s0 += e0; s1 += e1; s2 += e2; s3 += e3;
    }
    __syncthreads();
    int j = 0;
    for (; j + 4 <= clen; j += 4) {
      unsigned oA = ((unsigned)s_src[j]     << 8) + loff;
      unsigned oB = ((unsigned)s_src[j + 1] << 8) + loff;
      unsigned oC = ((unsigned)s_src[j + 2] << 8) + loff;
      unsigned oD = ((unsigned)s_src[j + 3] << 8) + loff;
      unsigned rA = *(const unsigned*)&xh8[oA];
      unsigned rB = *(const unsigned*)&xh8[oB];
      unsigned rC = *(const unsigned*)&xh8[oC];
      unsigned rD = *(const unsigned*)&xh8[oD];
      float aA = s_al[j * 4 + h],       aB = s_al[(j + 1) * 4 + h];
      float aC = s_al[(j + 2) * 4 + h], aD = s_al[(j + 3) * 4 + h];
      f32x2 lA = __builtin_amdgcn_cvt_pk_f32_fp8((int)rA, 0);
      f32x2 hA = __builtin_amdgcn_cvt_pk_f32_fp8((int)rA, 1);
      f32x2 lB = __builtin_amdgcn_cvt_pk_f32_fp8((int)rB, 0);
      f32x2 hB = __builtin_amdgcn_cvt_pk_f32_fp8((int)rB, 1);
      f32x2 lC = __builtin_amdgcn_cvt_pk_f32_fp8((int)rC, 0);
      f32x2 hC = __builtin_amdgcn_cvt_pk_f32_fp8((int)rC, 1);
      f32x2 lD = __builtin_amdgcn_cvt_pk_f32_fp8((int)rD, 0);
      f32x2 hD = __builtin_amdgcn_cvt_pk_f32_fp8((int)rD, 1);
      acc0 += aA * lA[0] + aB * lB[0] + aC * lC[0] + aD * lD[0];
      acc1 += aA * lA[1] + aB * lB[1] + aC * lC[1] + aD * lD[1];
      acc2 += aA * hA[0] + aB * hB[0] + aC * hC[0] + aD * hD[0];
      acc3 += aA * hA[1] + aB * hB[1] + aC * hC[1] + aD * hD[1];
    }
    for (; j < clen; j++) {
      unsigned oA = ((unsigned)s_src[j] << 8) + loff;
      unsigned rA = *(const unsigned*)&xh8[oA];
      float aA = s_al[j * 4 + h];
      f32x2 lA = __builtin_amdgcn_cvt_pk_f32_fp8((int)rA, 0);
      f32x2 hA = __builtin_amdgcn_cvt_pk_f32_fp8((int)rA, 1);
      acc0 += aA * lA[0];
      acc1 += aA * lA[1];
      acc2 += aA * hA[0];
      acc3 += aA * hA[1];
    }
    __syncthreads();
  }

#pragma unroll
  for (int o = 32; o >= 1; o >>= 1) {
    s0 += __shfl_xor(s0, o, 64);
    s1 += __shfl_xor(s1, o, 64);
    s2 += __shfl_xor(s2, o, 64);
    s3 += __shfl_xor(s3, o, 64);
  }
  float i0 = 1.f / (s0 + 1e-16f), i1 = 1.f / (s1 + 1e-16f);
  float i2 = 1.f / (s2 + 1e-16f), i3 = 1.f / (s3 + 1e-16f);
  if (lane == 0) *(float4*)&den_inv[n * 4] = make_float4(i0, i1, i2, i3);

  float ivh = (h == 0) ? i0 : (h == 1) ? i1 : (h == 2) ? i2 : i3;
  int cb0 = (lane & 3) * 64 + (lane >> 2);
  s_tr[cb0 +  0] = __float2half(acc0 * ivh + gat_bias[cb0 +  0]);
  s_tr[cb0 + 16] = __float2half(acc1 * ivh + gat_bias[cb0 + 16]);
  s_tr[cb0 + 32] = __float2half(acc2 * ivh + gat_bias[cb0 + 32]);
  s_tr[cb0 + 48] = __float2half(acc3 * ivh + gat_bias[cb0 + 48]);
  __syncthreads();
  uint2 u = *(const uint2*)&s_tr[4 * lane];
  *(uint2*)&x2h[(size_t)n * 256 + 4 * lane] = u;
}

// ---------------- K4 fused: alpha (blocks < ABLK) | stats1 partials (rest) ----
__global__ __launch_bounds__(256) void k_alst(const int* __restrict__ ei,
                                              const float* __restrict__ a_src_n,
                                              const float* __restrict__ a_dst_n,
                                              const float* __restrict__ den_inv,
                                              float* __restrict__ alpha_out,
                                              const __half* __restrict__ x2h,
                                              const int* __restrict__ gcnt,
                                              const int* __restrict__ goff,
                                              float* __restrict__ psumA,
                                              float* __restrict__ psumB) {
  if (blockIdx.x < ABLK) {
    int idx = blockIdx.x * 256 + threadIdx.x;
    if (idx >= NE + NN) return;
    int s, d;
    if (idx < NE) { s = ei[idx]; d = ei[NE + idx]; }
    else          { s = idx - NE; d = s; }
    float4 as = *(const float4*)&a_src_n[s * 4];
    float4 ad = *(const float4*)&a_dst_n[d * 4];
    float4 iv = *(const float4*)&den_inv[d * 4];
    float4 a;
    a.x = __expf(lrelu(as.x + ad.x)) * iv.x;
    a.y = __expf(lrelu(as.y + ad.y)) * iv.y;
    a.z = __expf(lrelu(as.z + ad.z)) * iv.z;
    a.w = __expf(lrelu(as.w + ad.w)) * iv.w;
    *(float4*)&alpha_out[(size_t)idx * 4] = a;
  } else {
    int b = blockIdx.x - ABLK, c = threadIdx.x;
    int g = b >> 3, s = b & 7;
    int cnt = gcnt[g], start = goff[g];
    const __half* p = x2h + (size_t)start * 256 + c;
    float sum = 0.f, sum2 = 0.f;
    int i = s;
    for (; i + 56 < cnt; i += 64) {
      float v0 = __half2float(p[(size_t)(i +  0) * 256]);
      float v1 = __half2float(p[(size_t)(i +  8) * 256]);
      float v2 = __half2float(p[(size_t)(i + 16) * 256]);
      float v3 = __half2float(p[(size_t)(i + 24) * 256]);
      float v4 = __half2float(p[(size_t)(i + 32) * 256]);
      float v5 = __half2float(p[(size_t)(i + 40) * 256]);
      float v6 = __half2float(p[(size_t)(i + 48) * 256]);
      float v7 = __half2float(p[(size_t)(i + 56) * 256]);
      sum += ((v0 + v1) + (v2 + v3)) + ((v4 + v5) + (v6 + v7));
      sum2 += ((v0 * v0 + v1 * v1) + (v2 * v2 + v3 * v3)) +
              ((v4 * v4 + v5 * v5) + (v6 * v6 + v7 * v7));
    }
    for (; i < cnt; i += 8) { float v = __half2float(p[(size_t)i * 256]); sum += v; sum2 += v * v; }
    psumA[b * 256 + c] = sum;
    psumB[b * 256 + c] = sum2;
  }
}

// ---------------- K5: finalize scale/shift -----------------------------------
__global__ __launch_bounds__(256) void k_stats2(const float* __restrict__ psumA,
                                                const float* __restrict__ psumB,
                                                const int* __restrict__ gcnt,
                                                const float* __restrict__ gn_w,
                                                const float* __restrict__ gn_b,
                                                const float* __restrict__ gn_ms,
                                                float* __restrict__ scale_g,
                                                float* __restrict__ shift_g) {
  int g = blockIdx.x, c = threadIdx.x;
  int b0 = g * SPLIT;
  float S = 0.f, S2 = 0.f;
#pragma unroll
  for (int k = 0; k < SPLIT; k++) {
    S  += psumA[(b0 + k) * 256 + c];
    S2 += psumB[(b0 + k) * 256 + c];
  }
  float fc = fmaxf((float)gcnt[g], 1.f);
  float mean = S / fc;
  float mm = mean * gn_ms[c];
  float var = fmaxf(S2 / fc - 2.f * mm * mean + mm * mm, 0.f);
  float sc = gn_w[c] / sqrtf(var + GEPS);
  scale_g[g * 256 + c] = sc;
  shift_g[g * 256 + c] = gn_b[c] - sc * mm;
}

// ---------------- K6: gate MLP via MFMA (16 nodes / wave) --------------------
__global__ __launch_bounds__(256) void k_gate(const __half* __restrict__ x2h,
                                              const int* __restrict__ batch,
                                              const float* __restrict__ scale_g,
                                              const float* __restrict__ shift_g,
                                              const _Float16* __restrict__ a1w,
                                              const float* __restrict__ att1_b,
                                              const float* __restrict__ att2_w,
                                              const float* __restrict__ att2_b,
                                              float* __restrict__ gate_raw) {
  int w = threadIdx.x >> 6, lane = threadIdx.x & 63;
  int nb = blockIdx.x * 64 + w * 16;
  if (nb >= NN) return;                 // no barriers -> safe
  int am = lane & 15, quad = lane >> 4;
  int node = nb + am;
  int g = batch[node];

  const __half*   xp  = x2h + (size_t)node * 256 + quad * 8;
  const float*    scp = scale_g + g * 256 + quad * 8;
  const float*    shp = shift_g + g * 256 + quad * 8;
  const _Float16* bp  = a1w + am * 256 + quad * 8;

  f32x4 acc = (f32x4){0.f, 0.f, 0.f, 0.f};
#pragma unroll
  for (int kb = 0; kb < 8; kb++) {
    f16x8 xv = *(const f16x8*)(xp + kb * 32);
    float4 sc0 = *(const float4*)(scp + kb * 32);
    float4 sc1 = *(const float4*)(scp + kb * 32 + 4);
    float4 sh0 = *(const float4*)(shp + kb * 32);
    float4 sh1 = *(const float4*)(shp + kb * 32 + 4);
    f16x8 a;
    a[0] = (_Float16)fmaxf(sc0.x * (float)xv[0] + sh0.x, 0.f);
    a[1] = (_Float16)fmaxf(sc0.y * (float)xv[1] + sh0.y, 0.f);
    a[2] = (_Float16)fmaxf(sc0.z * (float)xv[2] + sh0.z, 0.f);
    a[3] = (_Float16)fmaxf(sc0.w * (float)xv[3] + sh0.w, 0.f);
    a[4] = (_Float16)fmaxf(sc1.x * (float)xv[4] + sh1.x, 0.f);
    a[5] = (_Float16)fmaxf(sc1.y * (float)xv[5] + sh1.y, 0.f);
    a[6] = (_Float16)fmaxf(sc1.z * (float)xv[6] + sh1.z, 0.f);
    a[7] = (_Float16)fmaxf(sc1.w * (float)xv[7] + sh1.w, 0.f);
    f16x8 b = *(const f16x8*)(bp + kb * 32);
    acc = __builtin_amdgcn_mfma_f32_16x16x32_f16(a, b, acc, 0, 0, 0);
  }

  float b1 = att1_b[am], w2 = att2_w[am], b2 = att2_b[0];
#pragma unroll
  for (int r = 0; r < 4; r++) {
    float t = w2 * fmaxf(acc[r] + b1, 0.f);
#pragma unroll
    for (int o = 1; o < 16; o <<= 1) t += __shfl_xor(t, o, 64);
    if (am == 0) gate_raw[nb + quad * 4 + r] = 1.f / (1.f + __expf(-(t + b2)));
  }
}

// ---------------- K7: weighted pool partials w/ inline gate softmax ----------
__global__ __launch_bounds__(256) void k_poolp(const __half* __restrict__ x2h,
                                               const float* __restrict__ gate_raw,
                                               const int* __restrict__ gcnt,
                                               const int* __restrict__ goff,
                                               const float* __restrict__ scale_g,
                                               const float* __restrict__ shift_g,
                                               float* __restrict__ ppool) {
  __shared__ float s_w[1024];
  __shared__ float red[4];
  int b = blockIdx.x, c = threadIdx.x, lane = c & 63, wid = c >> 6;
  int g = b >> 3, s = b & 7;
  int cnt = gcnt[g], start = goff[g];
  float ls = 0.f;
  for (int i = c; i < cnt; i += 256) {
    float e = __expf(gate_raw[start + i]);
    s_w[i] = e;
    ls += e;
  }
#pragma unroll
  for (int o = 32; o >= 1; o >>= 1) ls += __shfl_xor(ls, o, 64);
  if (lane == 0) red[wid] = ls;
  __syncthreads();
  float rden = 1.f / (red[0] + red[1] + red[2] + red[3] + 1e-16f);

  float sc = scale_g[g * 256 + c], sh = shift_g[g * 256 + c];
  const __half* p = x2h + (size_t)start * 256 + c;
  float pooled = 0.f;
  int i = s;
  for (; i + 56 < cnt; i += 64) {
    float v0 = __half2float(p[(size_t)(i +  0) * 256]);
    float v1 = __half2float(p[(size_t)(i +  8) * 256]);
    float v2 = __half2float(p[(size_t)(i + 16) * 256]);
    float v3 = __half2float(p[(size_t)(i + 24) * 256]);
    float v4 = __half2float(p[(size_t)(i + 32) * 256]);
    float v5 = __half2float(p[(size_t)(i + 40) * 256]);
    float v6 = __half2float(p[(size_t)(i + 48) * 256]);
    float v7 = __half2float(p[(size_t)(i + 56) * 256]);
    pooled += s_w[i +  0] * fmaxf(sc * v0 + sh, 0.f);
    pooled += s_w[i +  8] * fmaxf(sc * v1 + sh, 0.f);
    pooled += s_w[i + 16] * fmaxf(sc * v2 + sh, 0.f);
    pooled += s_w[i + 24] * fmaxf(sc * v3 + sh, 0.f);
    pooled += s_w[i + 32] * fmaxf(sc * v4 + sh, 0.f);
    pooled += s_w[i + 40] * fmaxf(sc * v5 + sh, 0.f);
    pooled += s_w[i + 48] * fmaxf(sc * v6 + sh, 0.f);
    pooled += s_w[i + 56] * fmaxf(sc * v7 + sh, 0.f);
  }
  for (; i < cnt; i += 8)
    pooled += s_w[i] * fmaxf(sc * __half2float(p[(size_t)i * 256]) + sh, 0.f);
  ppool[b * 256 + c] = pooled * rden;
}

// ---------------- K8: reduce pool partials + fc1 + out head ------------------
__global__ __launch_bounds__(256) void k_fin(const float* __restrict__ ppool,
                                             const float* __restrict__ fc1_w,
                                             const float* __restrict__ fc1_b,
                                             const float* __restrict__ out_w,
                                             const float* __restrict__ out_b,
                                             float* __restrict__ outp) {
  __shared__ __align__(16) float pool_s[256];
  __shared__ float hred[128];
  __shared__ float red[4];
  int g = blockIdx.x, tid = threadIdx.x, lane = tid & 63, wid = tid >> 6;
  int b0 = g * SPLIT;
  float acc = 0.f;
#pragma unroll
  for (int k = 0; k < SPLIT; k++) acc += ppool[(b0 + k) * 256 + tid];
  pool_s[tid] = acc;
  __syncthreads();
  float4 psv = *(const float4*)&pool_s[4 * lane];
  for (int j0 = 0; j0 < 32; j0++) {
    int j = wid * 32 + j0;
    float4 w = *(const float4*)&fc1_w[j * 256 + 4 * lane];
    float d = w.x * psv.x + w.y * psv.y + w.z * psv.z + w.w * psv.w;
#pragma unroll
    for (int o = 32; o >= 1; o >>= 1) d += __shfl_xor(d, o, 64);
    if (lane == 0) hred[j] = fmaxf(d + fc1_b[j], 0.f) * out_w[j];
  }
  __syncthreads();
  if (tid < 128) {
    float v = hred[tid];
#pragma unroll
    for (int o = 32; o >= 1; o >>= 1) v += __shfl_xor(v, o, 64);
    if (lane == 0) red[wid] = v;
  }
  __syncthreads();
  if (tid == 0) outp[g] = 1.f / (1.f + __expf(-(red[0] + red[1] + out_b[0])));
}

// -----------------------------------------------------------------------------
extern "C" void kernel_launch(void* const* d_in, const int* in_sizes, int n_in,
                              void* d_out, int out_size, void* d_ws, size_t ws_size,
                              hipStream_t stream) {
  const float* x        = (const float*)d_in[0];
  const int*   ei       = (const int*)d_in[1];
  const int*   batch    = (const int*)d_in[2];
  const float* lin_w    = (const float*)d_in[3];
  const float* att_src  = (const float*)d_in[4];
  const float* att_dst  = (const float*)d_in[5];
  const float* gat_bias = (const float*)d_in[6];
  const float* gn_w     = (const float*)d_in[7];
  const float* gn_b     = (const float*)d_in[8];
  const float* gn_ms    = (const float*)d_in[9];
  const float* fc1_w    = (const float*)d_in[10];
  const float* fc1_b    = (const float*)d_in[11];
  const float* out_w    = (const float*)d_in[12];
  const float* out_b    = (const float*)d_in[13];
  const float* att1_w   = (const float*)d_in[14];
  const float* att1_b   = (const float*)d_in[15];
  const float* att2_w   = (const float*)d_in[16];
  const float* att2_b   = (const float*)d_in[17];

  float* outp  = (float*)d_out;       // [256]
  float* alpha = outp + NG;           // [(E+N)*4]

  char* wsb = (char*)d_ws;
  size_t o = 0;
  auto A = [&](size_t bytes) -> char* {
    char* p = wsb + o;
    o += (bytes + 255) & ~(size_t)255;
    return p;
  };
  unsigned char* xh8 = (unsigned char*)A((size_t)NN * 256);
  __half*   x2h      = (__half*)A((size_t)NN * 256 * 2);
  _Float16* wh       = (_Float16*)A((size_t)256 * 64 * 2);
  _Float16* a1w      = (_Float16*)A((size_t)16 * 256 * 2);
  float* a_src_n  = (float*)A((size_t)NN * 4 * 4);
  float* a_dst_n  = (float*)A((size_t)NN * 4 * 4);
  float* den_inv  = (float*)A((size_t)NN * 4 * 4);
  float* gate_raw = (float*)A((size_t)NN * 4);
  float* psumA    = (float*)A((size_t)NG * SPLIT * 256 * 4);
  float* psumB    = (float*)A((size_t)NG * SPLIT * 256 * 4);
  float* ppool    = (float*)A((size_t)NG * SPLIT * 256 * 4);
  float* scale_g  = (float*)A((size_t)NG * 256 * 4);
  float* shift_g  = (float*)A((size_t)NG * 256 * 4);
  int*   deg      = (int*)A((size_t)NN * 4);
  int*   gcnt     = (int*)A((size_t)NG * 4);
  int*   offs     = (int*)A((size_t)NN * 4);
  int*   goff     = (int*)A((size_t)NG * 4);
  int*   src_list = (int*)A((size_t)NE * 4);
  int2*  ebuf     = (int2*)A((size_t)NB * CAP * 8);
  int*   bucket_cnt  = (int*)A((size_t)NB * 4);

  k_misc<<<21, 256, 0, stream>>>(lin_w, wh, att1_w, a1w, batch, goff, gcnt, bucket_cnt);
  k_linbin<<<NLINB + 256, 256, 0, stream>>>(x, wh, att_src, att_dst, xh8, a_src_n, a_dst_n,
                                            ei, bucket_cnt, ebuf);
  k_binB<<<NB, 256, 0, stream>>>(ebuf, bucket_cnt, deg, offs, src_list);
  k_gat<<<NN, 64, 0, stream>>>(xh8, a_src_n, a_dst_n, offs, deg, src_list,
                               gat_bias, x2h, den_inv);
  k_alst<<<ABLK + NG * SPLIT, 256, 0, stream>>>(ei, a_src_n, a_dst_n, den_inv, alpha,
                                                x2h, gcnt, goff, psumA, psumB);
  k_stats2<<<NG, 256, 0, stream>>>(psumA, psumB, gcnt, gn_w, gn_b, gn_ms, scale_g, shift_g);
  k_gate<<<(NN + 63) / 64, 256, 0, stream>>>(x2h, batch, scale_g, shift_g, a1w, att1_b,
                                             att2_w, att2_b, gate_raw);
  k_poolp<<<NG * SPLIT, 256, 0, stream>>>(x2h, gate_raw, gcnt, goff, scale_g, shift_g, ppool);
  k_fin<<<NG, 256, 0, stream>>>(ppool, fc1_w, fc1_b, out_w, out_b, outp);
}